// Round 6
// baseline (930.373 us; speedup 1.0000x reference)
//
#include <hip/hip_runtime.h>
#include <hip/hip_bf16.h>

// GCN, bf16 node features + fp32 accumulation.
//  CSR build -> k_mm1 (lane=row gather GEMM, j-split x2)
//  3x k_aggs: XCD-pinned 16-feature column slice (L2-resident gathers),
//             lane = 4 edges x 16 features, shfl edge distribution.
//  2x k_mm64 (lane=row, K=64 bf16, j-split x2)
//  k_pool (mean pool + MLP + sigmoid)

typedef unsigned short u16;
typedef unsigned int u32;

__device__ __forceinline__ float bf2f(u32 u) {
  return __uint_as_float(u << 16);
}
__device__ __forceinline__ u16 f2bf(float f) {
  u32 x = __float_as_uint(f);
  return (u16)((x + 0x7fffu + ((x >> 16) & 1u)) >> 16);  // RNE
}

// ---------------- CSR build ----------------
__global__ __launch_bounds__(256) void k_zero(int* __restrict__ p, int n) {
  int i = blockIdx.x * blockDim.x + threadIdx.x;
  for (; i < n; i += gridDim.x * blockDim.x) p[i] = 0;
}

__global__ __launch_bounds__(256) void k_count(const int* __restrict__ dst, int* __restrict__ cnt, int e_count) {
  int e = blockIdx.x * blockDim.x + threadIdx.x;
  if (e < e_count) atomicAdd(&cnt[dst[e]], 1);
}

__global__ __launch_bounds__(256) void k_scan1(const int* __restrict__ cnt, int n, int* __restrict__ bsum) {
  __shared__ int s[256];
  int b = blockIdx.x, t = threadIdx.x;
  int base = b * 1024;
  int sum = 0;
  #pragma unroll
  for (int i = 0; i < 4; ++i) {
    int idx = base + t + i * 256;
    if (idx < n) sum += cnt[idx];
  }
  s[t] = sum; __syncthreads();
  for (int off = 128; off > 0; off >>= 1) {
    if (t < off) s[t] += s[t + off];
    __syncthreads();
  }
  if (t == 0) bsum[b] = s[0];
}

__global__ __launch_bounds__(128) void k_scan2(int* __restrict__ bsum, int nb, int* __restrict__ total_out) {
  __shared__ int sh[128];
  int t = threadIdx.x;
  sh[t] = (t < nb) ? bsum[t] : 0;
  __syncthreads();
  for (int off = 1; off < 128; off <<= 1) {
    int x = sh[t];
    int y = (t >= off) ? sh[t - off] : 0;
    __syncthreads();
    sh[t] = x + y;
    __syncthreads();
  }
  if (t < nb) bsum[t] = (t == 0) ? 0 : sh[t - 1];
  if (t == 0) *total_out = sh[127];
}

__global__ __launch_bounds__(256) void k_scan3(const int* __restrict__ cnt, int n,
                                               const int* __restrict__ bsum_ex, int* __restrict__ offsets,
                                               float* __restrict__ dinv) {
  __shared__ int sh[256];
  int b = blockIdx.x, t = threadIdx.x;
  int base = b * 1024 + t * 4;
  int v0 = (base + 0 < n) ? cnt[base + 0] : 0;
  int v1 = (base + 1 < n) ? cnt[base + 1] : 0;
  int v2 = (base + 2 < n) ? cnt[base + 2] : 0;
  int v3 = (base + 3 < n) ? cnt[base + 3] : 0;
  if (base + 0 < n) dinv[base + 0] = rsqrtf((float)v0 + 1.0f);
  if (base + 1 < n) dinv[base + 1] = rsqrtf((float)v1 + 1.0f);
  if (base + 2 < n) dinv[base + 2] = rsqrtf((float)v2 + 1.0f);
  if (base + 3 < n) dinv[base + 3] = rsqrtf((float)v3 + 1.0f);
  sh[t] = v0 + v1 + v2 + v3;
  __syncthreads();
  for (int off = 1; off < 256; off <<= 1) {
    int x = sh[t];
    int y = (t >= off) ? sh[t - off] : 0;
    __syncthreads();
    sh[t] = x + y;
    __syncthreads();
  }
  int run = bsum_ex[b] + ((t == 0) ? 0 : sh[t - 1]);
  if (base + 0 < n) offsets[base + 0] = run; run += v0;
  if (base + 1 < n) offsets[base + 1] = run; run += v1;
  if (base + 2 < n) offsets[base + 2] = run; run += v2;
  if (base + 3 < n) offsets[base + 3] = run;
}

__global__ __launch_bounds__(256) void k_scatter(const int* __restrict__ src, const int* __restrict__ dst,
                                                 const float* __restrict__ dinv, const int* __restrict__ offsets,
                                                 int* __restrict__ cursor, int2* __restrict__ csr, int e_count) {
  int e = blockIdx.x * blockDim.x + threadIdx.x;
  if (e >= e_count) return;
  int s = src[e], d = dst[e];
  int pos = offsets[d] + atomicAdd(&cursor[d], 1);
  csr[pos] = make_int2(s, __float_as_int(dinv[s] * dinv[d]));
}

// ---------------- layer-1 GEMM: out[r][j] = sum_k emb[ids[r]][k] * W1[k][j] ----------------
// lane = row; jb = blockIdx&1 selects 32-wide j half (grid x2 for latency hiding).
__global__ __launch_bounds__(64) void k_mm1(const int* __restrict__ ids,
                                            const float* __restrict__ emb,
                                            const float* __restrict__ W1,
                                            u16* __restrict__ out, int n) {
  const int lane = threadIdx.x;
  const int jb = blockIdx.x & 1;
  const int r = (blockIdx.x >> 1) * 64 + lane;
  const int rid = ids[(r < n) ? r : (n - 1)];
  const float4* __restrict__ xrow = reinterpret_cast<const float4*>(emb + (size_t)rid * 128);
  const float* __restrict__ Wb = W1 + jb * 32;

  float acc[32];
  #pragma unroll
  for (int j = 0; j < 32; ++j) acc[j] = 0.f;
  #pragma unroll 4
  for (int k4 = 0; k4 < 32; ++k4) {
    float4 xv = xrow[k4];
    const float* __restrict__ w0 = Wb + (k4 * 4) * 64;
    #pragma unroll
    for (int j = 0; j < 32; ++j) {
      acc[j] = fmaf(xv.x, w0[j], acc[j]);
      acc[j] = fmaf(xv.y, w0[64 + j], acc[j]);
      acc[j] = fmaf(xv.z, w0[128 + j], acc[j]);
      acc[j] = fmaf(xv.w, w0[192 + j], acc[j]);
    }
  }
  if (r < n) {
    u16* op = out + (size_t)r * 64 + jb * 32;
    #pragma unroll
    for (int j8 = 0; j8 < 4; ++j8) {
      uint4 pk;
      pk.x = ((u32)f2bf(acc[j8 * 8 + 1]) << 16) | f2bf(acc[j8 * 8 + 0]);
      pk.y = ((u32)f2bf(acc[j8 * 8 + 3]) << 16) | f2bf(acc[j8 * 8 + 2]);
      pk.z = ((u32)f2bf(acc[j8 * 8 + 5]) << 16) | f2bf(acc[j8 * 8 + 4]);
      pk.w = ((u32)f2bf(acc[j8 * 8 + 7]) << 16) | f2bf(acc[j8 * 8 + 6]);
      *reinterpret_cast<uint4*>(op + j8 * 8) = pk;
    }
  }
}

// ---------------- K=64 GEMM (bf16 in): out[r][j] = sum_k X[r][k] * W[k][j] ----------------
__global__ __launch_bounds__(64) void k_mm64(const u16* __restrict__ X,
                                             const float* __restrict__ W,
                                             u16* __restrict__ out, int n) {
  const int lane = threadIdx.x;
  const int jb = blockIdx.x & 1;
  const int r = (blockIdx.x >> 1) * 64 + lane;
  const uint4* __restrict__ xp = reinterpret_cast<const uint4*>(X + (size_t)((r < n) ? r : (n - 1)) * 64);
  const float* __restrict__ Wb = W + jb * 32;

  float acc[32];
  #pragma unroll
  for (int j = 0; j < 32; ++j) acc[j] = 0.f;
  #pragma unroll
  for (int c = 0; c < 8; ++c) {
    uint4 u = xp[c];  // 8 bf16: k = 8c..8c+7
    float f0 = bf2f(u.x & 0xffffu), f1 = bf2f(u.x >> 16);
    float f2 = bf2f(u.y & 0xffffu), f3 = bf2f(u.y >> 16);
    float f4 = bf2f(u.z & 0xffffu), f5 = bf2f(u.z >> 16);
    float f6 = bf2f(u.w & 0xffffu), f7 = bf2f(u.w >> 16);
    const float* __restrict__ w0 = Wb + (c * 8) * 64;
    #pragma unroll
    for (int j = 0; j < 32; ++j) {
      acc[j] = fmaf(f0, w0[j], acc[j]);
      acc[j] = fmaf(f1, w0[64 + j], acc[j]);
      acc[j] = fmaf(f2, w0[128 + j], acc[j]);
      acc[j] = fmaf(f3, w0[192 + j], acc[j]);
      acc[j] = fmaf(f4, w0[256 + j], acc[j]);
      acc[j] = fmaf(f5, w0[320 + j], acc[j]);
      acc[j] = fmaf(f6, w0[384 + j], acc[j]);
      acc[j] = fmaf(f7, w0[448 + j], acc[j]);
    }
  }
  if (r < n) {
    u16* op = out + (size_t)r * 64 + jb * 32;
    #pragma unroll
    for (int j8 = 0; j8 < 4; ++j8) {
      uint4 pk;
      pk.x = ((u32)f2bf(acc[j8 * 8 + 1]) << 16) | f2bf(acc[j8 * 8 + 0]);
      pk.y = ((u32)f2bf(acc[j8 * 8 + 3]) << 16) | f2bf(acc[j8 * 8 + 2]);
      pk.z = ((u32)f2bf(acc[j8 * 8 + 5]) << 16) | f2bf(acc[j8 * 8 + 4]);
      pk.w = ((u32)f2bf(acc[j8 * 8 + 7]) << 16) | f2bf(acc[j8 * 8 + 6]);
      *reinterpret_cast<uint4*>(op + j8 * 8) = pk;
    }
  }
}

// ---------------- sliced aggregation ----------------
// slice s = (blockIdx&7)>>1  -> XCD-pinned 16-feature slice (3.2 MB, L2-resident).
// lane = eg*16 + f (eg: 4 edge groups, f: 16 features). 4 nodes per wave-iter.
// out[v][soff+f] = relu(xw[v][soff+f]*dinv^2 + b + sum coef*xw[src][soff+f])

#define AGG_NODE(ACC, STOP)                                                   \
  {                                                                           \
    int stop_ = ((STOP) < chunk_end) ? (STOP) : chunk_end;                    \
    for (; pos < stop_; pos += 4) {                                           \
      int ei = pos + eg;                                                      \
      int idx = (ei - e) & 63;                                                \
      int sb = __shfl(cex, idx, 64);                                          \
      float cf = __int_as_float(__shfl(cey, idx, 64));                        \
      cf = (ei < stop_) ? cf : 0.f;                                           \
      float xv = bf2f((u32)xw[(size_t)sb * 64 + soff + f]);                   \
      ACC = fmaf(xv, cf, ACC);                                                \
    }                                                                         \
    pos = stop_;                                                              \
  }

__global__ __launch_bounds__(256) void k_aggs(const u16* __restrict__ xw, const long long* __restrict__ csr,
                                              const int* __restrict__ offs, const float* __restrict__ dinv,
                                              const float* __restrict__ bias, u16* __restrict__ out, int n) {
  const int tid = threadIdx.x;
  const int lane = tid & 63;
  const int w = tid >> 6;
  const int f = lane & 15;
  const int eg = lane >> 4;
  const int s = (blockIdx.x & 7) >> 1;
  const int soff = s * 16;
  const int srank = ((blockIdx.x >> 3) << 1) | (blockIdx.x & 1);  // 0..511
  const int ngroups = (n + 3) >> 2;

  for (int grp = srank * 4 + w; grp < ngroups; grp += 2048) {
    const int v0 = grp * 4;
    const int c1 = (v0 + 1 < n) ? v0 + 1 : n;
    const int c2 = (v0 + 2 < n) ? v0 + 2 : n;
    const int c3 = (v0 + 3 < n) ? v0 + 3 : n;
    const int b0 = offs[v0], b1 = offs[c1], b2 = offs[c2], b3 = offs[c3];
    const int b4 = offs[(v0 + 4 < n) ? v0 + 4 : n];

    float acc0 = 0.f, acc1 = 0.f, acc2 = 0.f, acc3 = 0.f;
    int e = b0, pos = b0;
    while (e < b4) {
      int cnt = b4 - e;
      cnt = (cnt < 64) ? cnt : 64;
      long long ll = 0;
      if (lane < cnt) ll = __builtin_nontemporal_load(&csr[e + lane]);
      int cex = (int)(ll & 0xffffffffll);
      int cey = (int)(ll >> 32);
      const int chunk_end = e + cnt;
      AGG_NODE(acc0, b1)
      AGG_NODE(acc1, b2)
      AGG_NODE(acc2, b3)
      AGG_NODE(acc3, b4)
      e = chunk_end;
    }

    // reduce across the 4 edge groups (lane bits 4,5)
    acc0 += __shfl_xor(acc0, 16, 64); acc0 += __shfl_xor(acc0, 32, 64);
    acc1 += __shfl_xor(acc1, 16, 64); acc1 += __shfl_xor(acc1, 32, 64);
    acc2 += __shfl_xor(acc2, 16, 64); acc2 += __shfl_xor(acc2, 32, 64);
    acc3 += __shfl_xor(acc3, 16, 64); acc3 += __shfl_xor(acc3, 32, 64);

    if (lane < 16) {
      const float bl = bias[soff + lane];
      {
        float d = dinv[v0];
        float h = fmaf(bf2f((u32)xw[(size_t)v0 * 64 + soff + lane]), d * d, bl) + acc0;
        __builtin_nontemporal_store(f2bf(fmaxf(h, 0.f)), &out[(size_t)v0 * 64 + soff + lane]);
      }
      if (c1 < n) {
        float d = dinv[c1];
        float h = fmaf(bf2f((u32)xw[(size_t)c1 * 64 + soff + lane]), d * d, bl) + acc1;
        __builtin_nontemporal_store(f2bf(fmaxf(h, 0.f)), &out[(size_t)c1 * 64 + soff + lane]);
      }
      if (c2 < n) {
        float d = dinv[c2];
        float h = fmaf(bf2f((u32)xw[(size_t)c2 * 64 + soff + lane]), d * d, bl) + acc2;
        __builtin_nontemporal_store(f2bf(fmaxf(h, 0.f)), &out[(size_t)c2 * 64 + soff + lane]);
      }
      if (c3 < n) {
        float d = dinv[c3];
        float h = fmaf(bf2f((u32)xw[(size_t)c3 * 64 + soff + lane]), d * d, bl) + acc3;
        __builtin_nontemporal_store(f2bf(fmaxf(h, 0.f)), &out[(size_t)c3 * 64 + soff + lane]);
      }
    }
  }
}

// ---------------- pooling + MLP head + sigmoid ----------------
__global__ __launch_bounds__(256) void k_pool(const u16* __restrict__ x, const int* __restrict__ batch, int n,
                                              const float* __restrict__ Wf1, const float* __restrict__ bf1,
                                              const float* __restrict__ Wf2, const float* __restrict__ bf2,
                                              float* __restrict__ out) {
  int g = blockIdx.x;
  int tid = threadIdx.x, lane = tid & 63, w = tid >> 6;
  int a = 0, b = n;
  while (a < b) { int m = (a + b) >> 1; if (batch[m] < g) a = m + 1; else b = m; }
  int lo = a;
  b = n;
  while (a < b) { int m = (a + b) >> 1; if (batch[m] < g + 1) a = m + 1; else b = m; }
  int hi = a;

  float acc = 0.f;
  for (int r = lo + w; r < hi; r += 4) acc += bf2f((u32)x[(size_t)r * 64 + lane]);
  __shared__ float red[4][64];
  __shared__ float mean[64];
  red[w][lane] = acc;
  __syncthreads();
  if (w == 0) {
    float s = red[0][lane] + red[1][lane] + red[2][lane] + red[3][lane];
    mean[lane] = s / fmaxf((float)(hi - lo), 1.0f);
  }
  __syncthreads();
  if (w == 0) {
    float h = bf1[lane];
    #pragma unroll
    for (int k = 0; k < 64; ++k) h = fmaf(mean[k], Wf1[k * 64 + lane], h);
    h = fmaxf(h, 0.f);
    float vv = h * Wf2[lane];
    for (int off = 32; off > 0; off >>= 1) vv += __shfl_down(vv, off, 64);
    if (lane == 0) out[g] = 1.0f / (1.0f + expf(-(vv + bf2[0])));
  }
}

static inline char* align256(char* p) {
  return (char*)(((uintptr_t)p + 255) & ~(uintptr_t)255);
}

extern "C" void kernel_launch(void* const* d_in, const int* in_sizes, int n_in,
                              void* d_out, int out_size, void* d_ws, size_t ws_size,
                              hipStream_t stream) {
  const int*   x_ids = (const int*)d_in[0];
  const int*   edge  = (const int*)d_in[1];
  const int*   batch = (const int*)d_in[2];
  const float* emb   = (const float*)d_in[3];
  const float* W1    = (const float*)d_in[4];
  const float* b1    = (const float*)d_in[5];
  const float* W2    = (const float*)d_in[6];
  const float* b2    = (const float*)d_in[7];
  const float* W3    = (const float*)d_in[8];
  const float* b3    = (const float*)d_in[9];
  const float* Wf1   = (const float*)d_in[10];
  const float* bf1   = (const float*)d_in[11];
  const float* Wf2   = (const float*)d_in[12];
  const float* bf2   = (const float*)d_in[13];
  float* out = (float*)d_out;

  const int N = in_sizes[0];
  const int E = in_sizes[1] / 2;
  const int G = out_size;
  const int* e_src = edge;
  const int* e_dst = edge + E;

  // workspace layout (bf16 feature buffers)
  char* p = (char*)d_ws;
  u16*   bufA = (u16*)p;              p = align256(p + (size_t)N * 64 * 2);
  u16*   bufB = (u16*)p;              p = align256(p + (size_t)N * 64 * 2);
  int2*  csr  = (int2*)p;             p = align256(p + (size_t)(E + 64) * 8);
  float* dinv = (float*)p;            p = align256(p + (size_t)N * 4);
  int*   cntcur = (int*)p;            p = align256(p + (size_t)2 * N * 4);
  int*   offs = (int*)p;              p = align256(p + (size_t)(N + 1) * 4);
  int*   bsum = (int*)p;              p = align256(p + (size_t)1024 * 4);
  int*   cnt = cntcur;
  int*   cur = cntcur + N;
  (void)ws_size; (void)n_in;

  const int nb_scan = (N + 1023) / 1024;  // 98 for N=100000 (<=128)
  dim3 blk(256);

  // CSR build
  k_zero<<<dim3(256), blk, 0, stream>>>(cntcur, 2 * N);
  k_count<<<dim3((E + 255) / 256), blk, 0, stream>>>(e_dst, cnt, E);
  k_scan1<<<dim3(nb_scan), blk, 0, stream>>>(cnt, N, bsum);
  k_scan2<<<dim3(1), dim3(128), 0, stream>>>(bsum, nb_scan, offs + N);
  k_scan3<<<dim3(nb_scan), blk, 0, stream>>>(cnt, N, bsum, offs, dinv);
  k_scatter<<<dim3((E + 255) / 256), blk, 0, stream>>>(e_src, e_dst, dinv, offs, cur, csr, E);

  const int mmgrid = 2 * ((N + 63) / 64);

  // layer 1
  k_mm1<<<dim3(mmgrid), dim3(64), 0, stream>>>(x_ids, emb, W1, bufA, N);
  k_aggs<<<dim3(2048), blk, 0, stream>>>(bufA, (const long long*)csr, offs, dinv, b1, bufB, N);
  // layer 2
  k_mm64<<<dim3(mmgrid), dim3(64), 0, stream>>>(bufB, W2, bufA, N);
  k_aggs<<<dim3(2048), blk, 0, stream>>>(bufA, (const long long*)csr, offs, dinv, b2, bufB, N);
  // layer 3
  k_mm64<<<dim3(mmgrid), dim3(64), 0, stream>>>(bufB, W3, bufA, N);
  k_aggs<<<dim3(2048), blk, 0, stream>>>(bufA, (const long long*)csr, offs, dinv, b3, bufB, N);

  // pool + MLP head
  k_pool<<<dim3(G), blk, 0, stream>>>(bufB, batch, N, Wf1, bf1, Wf2, bf2, out);
}

// Round 7
// 604.545 us; speedup vs baseline: 1.5390x; 1.5390x over previous
//
#include <hip/hip_runtime.h>
#include <hip/hip_bf16.h>

// GCN, bf16 node features + fp32 accumulation.
//  CSR build -> k_mm1 (lane=row gather GEMM, 4-wave j-split, L1-shared X)
//  3x k_agg<FINAL>: full-row gathers (1 line/edge), 16-edge masked batches,
//                   fused next-layer GEMM via readlane.
//  k_pool (mean pool + MLP + sigmoid)

typedef unsigned short u16;
typedef unsigned int u32;

__device__ __forceinline__ float bf2f(u32 u) {
  return __uint_as_float(u << 16);
}
__device__ __forceinline__ u16 f2bf(float f) {
  u32 x = __float_as_uint(f);
  return (u16)((x + 0x7fffu + ((x >> 16) & 1u)) >> 16);  // RNE
}

// ---------------- CSR build ----------------
__global__ __launch_bounds__(256) void k_zero(int* __restrict__ p, int n) {
  int i = blockIdx.x * blockDim.x + threadIdx.x;
  for (; i < n; i += gridDim.x * blockDim.x) p[i] = 0;
}

__global__ __launch_bounds__(256) void k_count(const int* __restrict__ dst, int* __restrict__ cnt, int e_count) {
  int e = blockIdx.x * blockDim.x + threadIdx.x;
  if (e < e_count) atomicAdd(&cnt[dst[e]], 1);
}

__global__ __launch_bounds__(256) void k_scan1(const int* __restrict__ cnt, int n, int* __restrict__ bsum) {
  __shared__ int s[256];
  int b = blockIdx.x, t = threadIdx.x;
  int base = b * 1024;
  int sum = 0;
  #pragma unroll
  for (int i = 0; i < 4; ++i) {
    int idx = base + t + i * 256;
    if (idx < n) sum += cnt[idx];
  }
  s[t] = sum; __syncthreads();
  for (int off = 128; off > 0; off >>= 1) {
    if (t < off) s[t] += s[t + off];
    __syncthreads();
  }
  if (t == 0) bsum[b] = s[0];
}

__global__ __launch_bounds__(128) void k_scan2(int* __restrict__ bsum, int nb, int* __restrict__ total_out) {
  __shared__ int sh[128];
  int t = threadIdx.x;
  sh[t] = (t < nb) ? bsum[t] : 0;
  __syncthreads();
  for (int off = 1; off < 128; off <<= 1) {
    int x = sh[t];
    int y = (t >= off) ? sh[t - off] : 0;
    __syncthreads();
    sh[t] = x + y;
    __syncthreads();
  }
  if (t < nb) bsum[t] = (t == 0) ? 0 : sh[t - 1];
  if (t == 0) *total_out = sh[127];
}

__global__ __launch_bounds__(256) void k_scan3(const int* __restrict__ cnt, int n,
                                               const int* __restrict__ bsum_ex, int* __restrict__ offsets,
                                               float* __restrict__ dinv) {
  __shared__ int sh[256];
  int b = blockIdx.x, t = threadIdx.x;
  int base = b * 1024 + t * 4;
  int v0 = (base + 0 < n) ? cnt[base + 0] : 0;
  int v1 = (base + 1 < n) ? cnt[base + 1] : 0;
  int v2 = (base + 2 < n) ? cnt[base + 2] : 0;
  int v3 = (base + 3 < n) ? cnt[base + 3] : 0;
  if (base + 0 < n) dinv[base + 0] = rsqrtf((float)v0 + 1.0f);
  if (base + 1 < n) dinv[base + 1] = rsqrtf((float)v1 + 1.0f);
  if (base + 2 < n) dinv[base + 2] = rsqrtf((float)v2 + 1.0f);
  if (base + 3 < n) dinv[base + 3] = rsqrtf((float)v3 + 1.0f);
  sh[t] = v0 + v1 + v2 + v3;
  __syncthreads();
  for (int off = 1; off < 256; off <<= 1) {
    int x = sh[t];
    int y = (t >= off) ? sh[t - off] : 0;
    __syncthreads();
    sh[t] = x + y;
    __syncthreads();
  }
  int run = bsum_ex[b] + ((t == 0) ? 0 : sh[t - 1]);
  if (base + 0 < n) offsets[base + 0] = run; run += v0;
  if (base + 1 < n) offsets[base + 1] = run; run += v1;
  if (base + 2 < n) offsets[base + 2] = run; run += v2;
  if (base + 3 < n) offsets[base + 3] = run;
}

__global__ __launch_bounds__(256) void k_scatter(const int* __restrict__ src, const int* __restrict__ dst,
                                                 const float* __restrict__ dinv, const int* __restrict__ offsets,
                                                 int* __restrict__ cursor, int2* __restrict__ csr, int e_count) {
  int e = blockIdx.x * blockDim.x + threadIdx.x;
  if (e >= e_count) return;
  int s = src[e], d = dst[e];
  int pos = offsets[d] + atomicAdd(&cursor[d], 1);
  csr[pos] = make_int2(s, __float_as_int(dinv[s] * dinv[d]));
}

// ---------------- layer-1 GEMM: out[r][j] = sum_k emb[ids[r]][k] * W1[k][j] ----------------
// Block = 4 waves over the SAME 64 rows (lane = row); wave w takes 16-wide j
// slice. The 4 waves issue identical per-lane X loads -> 3 of 4 are L1 hits;
// the 64-row tile (32 KB) fits L1 exactly.
__global__ __launch_bounds__(256) void k_mm1(const int* __restrict__ ids,
                                             const float* __restrict__ emb,
                                             const float* __restrict__ W1,
                                             u16* __restrict__ out, int n) {
  const int lane = threadIdx.x & 63;
  const int w = threadIdx.x >> 6;
  const int r = blockIdx.x * 64 + lane;
  const int rid = ids[(r < n) ? r : (n - 1)];
  const float4* __restrict__ xrow = reinterpret_cast<const float4*>(emb + (size_t)rid * 128);
  const float* __restrict__ Wb = W1 + w * 16;

  float acc[16];
  #pragma unroll
  for (int j = 0; j < 16; ++j) acc[j] = 0.f;
  #pragma unroll 4
  for (int k4 = 0; k4 < 32; ++k4) {
    float4 xv = xrow[k4];
    const float* __restrict__ w0 = Wb + (k4 * 4) * 64;
    #pragma unroll
    for (int j = 0; j < 16; ++j) {
      acc[j] = fmaf(xv.x, w0[j], acc[j]);
      acc[j] = fmaf(xv.y, w0[64 + j], acc[j]);
      acc[j] = fmaf(xv.z, w0[128 + j], acc[j]);
      acc[j] = fmaf(xv.w, w0[192 + j], acc[j]);
    }
  }
  if (r < n) {
    u16* op = out + (size_t)r * 64 + w * 16;
    uint4 pk;
    pk.x = ((u32)f2bf(acc[1]) << 16) | f2bf(acc[0]);
    pk.y = ((u32)f2bf(acc[3]) << 16) | f2bf(acc[2]);
    pk.z = ((u32)f2bf(acc[5]) << 16) | f2bf(acc[4]);
    pk.w = ((u32)f2bf(acc[7]) << 16) | f2bf(acc[6]);
    *reinterpret_cast<uint4*>(op) = pk;
    pk.x = ((u32)f2bf(acc[9]) << 16) | f2bf(acc[8]);
    pk.y = ((u32)f2bf(acc[11]) << 16) | f2bf(acc[10]);
    pk.z = ((u32)f2bf(acc[13]) << 16) | f2bf(acc[12]);
    pk.w = ((u32)f2bf(acc[15]) << 16) | f2bf(acc[14]);
    *reinterpret_cast<uint4*>(op + 8) = pk;
  }
}

// ---------------- fused aggregation + next-layer GEMM ----------------
// One wave per 4 consecutive nodes (contiguous CSR range). 64-edge chunk
// coalesced load; 16-edge sub-batches: 16 independent gathers issued
// back-to-back, node selection via wave-uniform masked coefs (4 FMA/edge).
// Phase 2 (lane = out col j): out_j = sum_k readlane(h,k) * W[k][j].

#define BATCH16(JB)                                                          \
  {                                                                          \
    float vv[16];                                                            \
    _Pragma("unroll")                                                        \
    for (int t = 0; t < 16; ++t) {                                           \
      int sb = __builtin_amdgcn_readlane(cex, (JB) + t);                     \
      vv[t] = bf2f((u32)xw[(size_t)sb * 64 + lane]);                         \
    }                                                                        \
    _Pragma("unroll")                                                        \
    for (int t = 0; t < 16; ++t) {                                           \
      int ei = e + (JB) + t;                                                 \
      float cf = __int_as_float(__builtin_amdgcn_readlane(cey, (JB) + t));   \
      float cf0 = (ei < b1) ? cf : 0.f;                                      \
      float cf1 = (ei >= b1 && ei < b2) ? cf : 0.f;                          \
      float cf2 = (ei >= b2 && ei < b3) ? cf : 0.f;                          \
      float cf3 = (ei >= b3) ? cf : 0.f;                                     \
      acc0 = fmaf(vv[t], cf0, acc0);                                         \
      acc1 = fmaf(vv[t], cf1, acc1);                                         \
      acc2 = fmaf(vv[t], cf2, acc2);                                         \
      acc3 = fmaf(vv[t], cf3, acc3);                                         \
    }                                                                        \
  }

template <bool FINAL>
__global__ __launch_bounds__(256) void k_agg(const u16* __restrict__ xw, const int2* __restrict__ csr,
                                             const int* __restrict__ offs, const float* __restrict__ dinv,
                                             const float* __restrict__ bias, const float* __restrict__ Wn,
                                             u16* __restrict__ out, int n) {
  const int lane = threadIdx.x & 63;
  const int w = threadIdx.x >> 6;
  const int ngroups = (n + 3) >> 2;
  const int grp = blockIdx.x * 4 + w;  // exactly one group per wave
  if (grp >= ngroups) return;

  const int v0 = grp * 4;
  const int c1 = (v0 + 1 < n) ? v0 + 1 : n;
  const int c2 = (v0 + 2 < n) ? v0 + 2 : n;
  const int c3 = (v0 + 3 < n) ? v0 + 3 : n;
  const int b0 = offs[v0], b1 = offs[c1], b2 = offs[c2], b3 = offs[c3];
  const int b4 = offs[(v0 + 4 < n) ? v0 + 4 : n];
  const float bl = bias[lane];

  float d0 = dinv[v0];
  float d1 = dinv[(c1 < n) ? c1 : v0];
  float d2 = dinv[(c2 < n) ? c2 : v0];
  float d3 = dinv[(c3 < n) ? c3 : v0];
  float acc0 = fmaf(bf2f((u32)xw[(size_t)v0 * 64 + lane]), d0 * d0, bl);
  float acc1 = (c1 < n) ? fmaf(bf2f((u32)xw[(size_t)c1 * 64 + lane]), d1 * d1, bl) : 0.f;
  float acc2 = (c2 < n) ? fmaf(bf2f((u32)xw[(size_t)c2 * 64 + lane]), d2 * d2, bl) : 0.f;
  float acc3 = (c3 < n) ? fmaf(bf2f((u32)xw[(size_t)c3 * 64 + lane]), d3 * d3, bl) : 0.f;

  int e = b0;
  while (e < b4) {
    int cnt = b4 - e;
    cnt = (cnt < 64) ? cnt : 64;
    int cex = 0, cey = 0;
    if (lane < cnt) {
      int2 ce = csr[e + lane];
      cex = ce.x; cey = ce.y;
    }
    for (int jb = 0; jb < cnt; jb += 16) {
      BATCH16(jb)
    }
    e += cnt;
  }

  float h0 = fmaxf(acc0, 0.f), h1 = fmaxf(acc1, 0.f);
  float h2 = fmaxf(acc2, 0.f), h3 = fmaxf(acc3, 0.f);
  if constexpr (FINAL) {
    out[(size_t)v0 * 64 + lane] = f2bf(h0);
    if (c1 < n) out[(size_t)c1 * 64 + lane] = f2bf(h1);
    if (c2 < n) out[(size_t)c2 * 64 + lane] = f2bf(h2);
    if (c3 < n) out[(size_t)c3 * 64 + lane] = f2bf(h3);
  } else {
    const int hb0 = __float_as_int(h0), hb1 = __float_as_int(h1);
    const int hb2 = __float_as_int(h2), hb3 = __float_as_int(h3);
    float o0 = 0.f, o1 = 0.f, o2 = 0.f, o3 = 0.f;
    #pragma unroll
    for (int k = 0; k < 64; ++k) {
      float wk = Wn[k * 64 + lane];
      o0 = fmaf(__int_as_float(__builtin_amdgcn_readlane(hb0, k)), wk, o0);
      o1 = fmaf(__int_as_float(__builtin_amdgcn_readlane(hb1, k)), wk, o1);
      o2 = fmaf(__int_as_float(__builtin_amdgcn_readlane(hb2, k)), wk, o2);
      o3 = fmaf(__int_as_float(__builtin_amdgcn_readlane(hb3, k)), wk, o3);
    }
    out[(size_t)v0 * 64 + lane] = f2bf(o0);
    if (c1 < n) out[(size_t)c1 * 64 + lane] = f2bf(o1);
    if (c2 < n) out[(size_t)c2 * 64 + lane] = f2bf(o2);
    if (c3 < n) out[(size_t)c3 * 64 + lane] = f2bf(o3);
  }
}

// ---------------- pooling + MLP head + sigmoid ----------------
__global__ __launch_bounds__(256) void k_pool(const u16* __restrict__ x, const int* __restrict__ batch, int n,
                                              const float* __restrict__ Wf1, const float* __restrict__ bf1,
                                              const float* __restrict__ Wf2, const float* __restrict__ bf2,
                                              float* __restrict__ out) {
  int g = blockIdx.x;
  int tid = threadIdx.x, lane = tid & 63, w = tid >> 6;
  int a = 0, b = n;
  while (a < b) { int m = (a + b) >> 1; if (batch[m] < g) a = m + 1; else b = m; }
  int lo = a;
  b = n;
  while (a < b) { int m = (a + b) >> 1; if (batch[m] < g + 1) a = m + 1; else b = m; }
  int hi = a;

  float acc = 0.f;
  for (int r = lo + w; r < hi; r += 4) acc += bf2f((u32)x[(size_t)r * 64 + lane]);
  __shared__ float red[4][64];
  __shared__ float mean[64];
  red[w][lane] = acc;
  __syncthreads();
  if (w == 0) {
    float s = red[0][lane] + red[1][lane] + red[2][lane] + red[3][lane];
    mean[lane] = s / fmaxf((float)(hi - lo), 1.0f);
  }
  __syncthreads();
  if (w == 0) {
    float h = bf1[lane];
    #pragma unroll
    for (int k = 0; k < 64; ++k) h = fmaf(mean[k], Wf1[k * 64 + lane], h);
    h = fmaxf(h, 0.f);
    float vv = h * Wf2[lane];
    for (int off = 32; off > 0; off >>= 1) vv += __shfl_down(vv, off, 64);
    if (lane == 0) out[g] = 1.0f / (1.0f + expf(-(vv + bf2[0])));
  }
}

static inline char* align256(char* p) {
  return (char*)(((uintptr_t)p + 255) & ~(uintptr_t)255);
}

extern "C" void kernel_launch(void* const* d_in, const int* in_sizes, int n_in,
                              void* d_out, int out_size, void* d_ws, size_t ws_size,
                              hipStream_t stream) {
  const int*   x_ids = (const int*)d_in[0];
  const int*   edge  = (const int*)d_in[1];
  const int*   batch = (const int*)d_in[2];
  const float* emb   = (const float*)d_in[3];
  const float* W1    = (const float*)d_in[4];
  const float* b1    = (const float*)d_in[5];
  const float* W2    = (const float*)d_in[6];
  const float* b2    = (const float*)d_in[7];
  const float* W3    = (const float*)d_in[8];
  const float* b3    = (const float*)d_in[9];
  const float* Wf1   = (const float*)d_in[10];
  const float* bf1   = (const float*)d_in[11];
  const float* Wf2   = (const float*)d_in[12];
  const float* bf2   = (const float*)d_in[13];
  float* out = (float*)d_out;

  const int N = in_sizes[0];
  const int E = in_sizes[1] / 2;
  const int G = out_size;
  const int* e_src = edge;
  const int* e_dst = edge + E;

  // workspace layout (bf16 feature buffers)
  char* p = (char*)d_ws;
  u16*   bufA = (u16*)p;              p = align256(p + (size_t)N * 64 * 2);
  u16*   bufB = (u16*)p;              p = align256(p + (size_t)N * 64 * 2);
  int2*  csr  = (int2*)p;             p = align256(p + (size_t)(E + 64) * 8);
  float* dinv = (float*)p;            p = align256(p + (size_t)N * 4);
  int*   cntcur = (int*)p;            p = align256(p + (size_t)2 * N * 4);
  int*   offs = (int*)p;              p = align256(p + (size_t)(N + 1) * 4);
  int*   bsum = (int*)p;              p = align256(p + (size_t)1024 * 4);
  int*   cnt = cntcur;
  int*   cur = cntcur + N;
  (void)ws_size; (void)n_in;

  const int nb_scan = (N + 1023) / 1024;  // 98 for N=100000 (<=128)
  dim3 blk(256);

  // CSR build
  k_zero<<<dim3(256), blk, 0, stream>>>(cntcur, 2 * N);
  k_count<<<dim3((E + 255) / 256), blk, 0, stream>>>(e_dst, cnt, E);
  k_scan1<<<dim3(nb_scan), blk, 0, stream>>>(cnt, N, bsum);
  k_scan2<<<dim3(1), dim3(128), 0, stream>>>(bsum, nb_scan, offs + N);
  k_scan3<<<dim3(nb_scan), blk, 0, stream>>>(cnt, N, bsum, offs, dinv);
  k_scatter<<<dim3((E + 255) / 256), blk, 0, stream>>>(e_src, e_dst, dinv, offs, cur, csr, E);

  const int ngroups = (N + 3) / 4;
  const int agg_grid = (ngroups + 3) / 4;

  // layer 1
  k_mm1<<<dim3((N + 63) / 64), blk, 0, stream>>>(x_ids, emb, W1, bufA, N);
  k_agg<false><<<dim3(agg_grid), blk, 0, stream>>>(bufA, csr, offs, dinv, b1, W2, bufB, N);
  k_agg<false><<<dim3(agg_grid), blk, 0, stream>>>(bufB, csr, offs, dinv, b2, W3, bufA, N);
  k_agg<true><<<dim3(agg_grid), blk, 0, stream>>>(bufA, csr, offs, dinv, b3, nullptr, bufB, N);

  // pool + MLP head
  k_pool<<<dim3(G), blk, 0, stream>>>(bufB, batch, N, Wf1, bf1, Wf2, bf2, out);
}

// Round 8
// 540.927 us; speedup vs baseline: 1.7200x; 1.1176x over previous
//
#include <hip/hip_runtime.h>
#include <hip/hip_bf16.h>

// GCN, bf16 node features + fp32 accumulation.
//  CSR build (trimmed) -> k_mm1 (lane=row, acc[64], scalar W, single gather pass)
//  3x k_agg<FINAL>: 4 nodes/wave, 64-edge chunk loads, 16/8/1 readlane batches,
//                   fused next-layer GEMM via readlane (measured free).
//  k_pool (mean pool + MLP + sigmoid)

typedef unsigned short u16;
typedef unsigned int u32;

__device__ __forceinline__ float bf2f(u32 u) {
  return __uint_as_float(u << 16);
}
__device__ __forceinline__ u16 f2bf(float f) {
  u32 x = __float_as_uint(f);
  return (u16)((x + 0x7fffu + ((x >> 16) & 1u)) >> 16);  // RNE
}

// ---------------- CSR build ----------------
__global__ __launch_bounds__(256) void k_zero(int* __restrict__ p, int n) {
  int i = blockIdx.x * blockDim.x + threadIdx.x;
  for (; i < n; i += gridDim.x * blockDim.x) p[i] = 0;
}

__global__ __launch_bounds__(256) void k_count(const int* __restrict__ dst, int* __restrict__ cnt, int e_count) {
  int e = blockIdx.x * blockDim.x + threadIdx.x;
  if (e < e_count) atomicAdd(&cnt[dst[e]], 1);
}

__global__ __launch_bounds__(256) void k_scan1(const int* __restrict__ cnt, int n, int* __restrict__ bsum) {
  __shared__ int s[256];
  int b = blockIdx.x, t = threadIdx.x;
  int base = b * 1024;
  int sum = 0;
  #pragma unroll
  for (int i = 0; i < 4; ++i) {
    int idx = base + t + i * 256;
    if (idx < n) sum += cnt[idx];
  }
  s[t] = sum; __syncthreads();
  for (int off = 128; off > 0; off >>= 1) {
    if (t < off) s[t] += s[t + off];
    __syncthreads();
  }
  if (t == 0) bsum[b] = s[0];
}

__global__ __launch_bounds__(128) void k_scan2(int* __restrict__ bsum, int nb, int* __restrict__ total_out) {
  __shared__ int sh[128];
  int t = threadIdx.x;
  sh[t] = (t < nb) ? bsum[t] : 0;
  __syncthreads();
  for (int off = 1; off < 128; off <<= 1) {
    int x = sh[t];
    int y = (t >= off) ? sh[t - off] : 0;
    __syncthreads();
    sh[t] = x + y;
    __syncthreads();
  }
  if (t < nb) bsum[t] = (t == 0) ? 0 : sh[t - 1];
  if (t == 0) *total_out = sh[127];
}

// scan3: emits offsets, a copy into cur (scatter cursor), and dinv.
__global__ __launch_bounds__(256) void k_scan3(const int* __restrict__ cnt, int n,
                                               const int* __restrict__ bsum_ex, int* __restrict__ offsets,
                                               int* __restrict__ cur, float* __restrict__ dinv) {
  __shared__ int sh[256];
  int b = blockIdx.x, t = threadIdx.x;
  int base = b * 1024 + t * 4;
  int v0 = (base + 0 < n) ? cnt[base + 0] : 0;
  int v1 = (base + 1 < n) ? cnt[base + 1] : 0;
  int v2 = (base + 2 < n) ? cnt[base + 2] : 0;
  int v3 = (base + 3 < n) ? cnt[base + 3] : 0;
  if (base + 0 < n) dinv[base + 0] = rsqrtf((float)v0 + 1.0f);
  if (base + 1 < n) dinv[base + 1] = rsqrtf((float)v1 + 1.0f);
  if (base + 2 < n) dinv[base + 2] = rsqrtf((float)v2 + 1.0f);
  if (base + 3 < n) dinv[base + 3] = rsqrtf((float)v3 + 1.0f);
  sh[t] = v0 + v1 + v2 + v3;
  __syncthreads();
  for (int off = 1; off < 256; off <<= 1) {
    int x = sh[t];
    int y = (t >= off) ? sh[t - off] : 0;
    __syncthreads();
    sh[t] = x + y;
    __syncthreads();
  }
  int run = bsum_ex[b] + ((t == 0) ? 0 : sh[t - 1]);
  if (base + 0 < n) { offsets[base + 0] = run; cur[base + 0] = run; } run += v0;
  if (base + 1 < n) { offsets[base + 1] = run; cur[base + 1] = run; } run += v1;
  if (base + 2 < n) { offsets[base + 2] = run; cur[base + 2] = run; } run += v2;
  if (base + 3 < n) { offsets[base + 3] = run; cur[base + 3] = run; }
}

__global__ __launch_bounds__(256) void k_scatter(const int* __restrict__ src, const int* __restrict__ dst,
                                                 const float* __restrict__ dinv,
                                                 int* __restrict__ cursor, int2* __restrict__ csr, int e_count) {
  int e = blockIdx.x * blockDim.x + threadIdx.x;
  if (e >= e_count) return;
  int s = src[e], d = dst[e];
  int pos = atomicAdd(&cursor[d], 1);
  csr[pos] = make_int2(s, __float_as_int(dinv[s] * dinv[d]));
}

// ---------------- layer-1 GEMM: out[r][j] = sum_k emb[ids[r]][k] * W1[k][j] ----------------
// lane = row, 1 wave/block, single pass: acc[64] (no j-split -> each row gathered
// once). 8 float4 row-loads staged per stage (8 outstanding per lane). W loads are
// lane-invariant -> compiler scalarizes to SMEM (proven round 7: VGPR=36).
__global__ __launch_bounds__(64, 4) void k_mm1(const int* __restrict__ ids,
                                               const float* __restrict__ emb,
                                               const float* __restrict__ W1,
                                               u16* __restrict__ out, int n) {
  const int lane = threadIdx.x;
  const int r = blockIdx.x * 64 + lane;
  const int rid = ids[(r < n) ? r : (n - 1)];
  const float4* __restrict__ xrow = reinterpret_cast<const float4*>(emb + (size_t)rid * 128);

  float acc[64];
  #pragma unroll
  for (int j = 0; j < 64; ++j) acc[j] = 0.f;

  #pragma unroll 1
  for (int s = 0; s < 4; ++s) {
    float4 xb[8];
    #pragma unroll
    for (int i = 0; i < 8; ++i) xb[i] = xrow[s * 8 + i];
    const float* __restrict__ wbase = W1 + (size_t)(s * 32) * 64;
    #pragma unroll
    for (int i = 0; i < 8; ++i) {
      const float* __restrict__ w0 = wbase + (i * 4) * 64;
      #pragma unroll
      for (int j = 0; j < 64; ++j) {
        acc[j] = fmaf(xb[i].x, w0[j], acc[j]);
        acc[j] = fmaf(xb[i].y, w0[64 + j], acc[j]);
        acc[j] = fmaf(xb[i].z, w0[128 + j], acc[j]);
        acc[j] = fmaf(xb[i].w, w0[192 + j], acc[j]);
      }
    }
  }

  if (r < n) {
    u16* op = out + (size_t)r * 64;
    #pragma unroll
    for (int q = 0; q < 8; ++q) {
      uint2 pk;
      pk.x = ((u32)f2bf(acc[q * 4 + 1]) << 16) | f2bf(acc[q * 4 + 0]);
      pk.y = ((u32)f2bf(acc[q * 4 + 3]) << 16) | f2bf(acc[q * 4 + 2]);
      // store 8B at a time to keep reg pressure flat
      *reinterpret_cast<uint2*>(op + q * 4) = pk;
    }
  }
}

// ---------------- fused aggregation + next-layer GEMM ----------------
// One wave per 4 consecutive nodes (contiguous CSR range). 64-edge chunk staged
// with one coalesced per-lane int2 load; readlane distribution; 16/8/1-wide
// batches per node segment. Phase 2: out_j = sum_k readlane(h,k)*W[k][j] (free).

#define AGG_BATCH16(ACC, O)                                                  \
  {                                                                          \
    float vv_[16], cc_[16];                                                  \
    _Pragma("unroll")                                                        \
    for (int t_ = 0; t_ < 16; ++t_) {                                        \
      int sb_ = __builtin_amdgcn_readlane(cex, (O) + t_);                    \
      cc_[t_] = __int_as_float(__builtin_amdgcn_readlane(cey, (O) + t_));    \
      vv_[t_] = bf2f((u32)xw[(size_t)sb_ * 64 + lane]);                      \
    }                                                                        \
    _Pragma("unroll")                                                        \
    for (int t_ = 0; t_ < 16; ++t_) ACC = fmaf(vv_[t_], cc_[t_], ACC);       \
  }

#define AGG_BATCH8(ACC, O)                                                   \
  {                                                                          \
    float vv_[8], cc_[8];                                                    \
    _Pragma("unroll")                                                        \
    for (int t_ = 0; t_ < 8; ++t_) {                                         \
      int sb_ = __builtin_amdgcn_readlane(cex, (O) + t_);                    \
      cc_[t_] = __int_as_float(__builtin_amdgcn_readlane(cey, (O) + t_));    \
      vv_[t_] = bf2f((u32)xw[(size_t)sb_ * 64 + lane]);                      \
    }                                                                        \
    _Pragma("unroll")                                                        \
    for (int t_ = 0; t_ < 8; ++t_) ACC = fmaf(vv_[t_], cc_[t_], ACC);        \
  }

#define AGG_ONE(ACC, O)                                                      \
  {                                                                          \
    int sb_ = __builtin_amdgcn_readlane(cex, (O));                           \
    float cf_ = __int_as_float(__builtin_amdgcn_readlane(cey, (O)));         \
    ACC = fmaf(bf2f((u32)xw[(size_t)sb_ * 64 + lane]), cf_, ACC);            \
  }

#define AGG_NODE(ACC, STOP)                                                  \
  {                                                                          \
    int stop_ = (STOP) < chunk_end ? (STOP) : chunk_end;                     \
    for (; pos + 16 <= stop_; pos += 16) AGG_BATCH16(ACC, pos - e)           \
    for (; pos + 8 <= stop_; pos += 8) AGG_BATCH8(ACC, pos - e)              \
    for (; pos < stop_; ++pos) AGG_ONE(ACC, pos - e)                         \
  }

template <bool FINAL>
__global__ __launch_bounds__(256) void k_agg(const u16* __restrict__ xw, const int2* __restrict__ csr,
                                             const int* __restrict__ offs, const float* __restrict__ dinv,
                                             const float* __restrict__ bias, const float* __restrict__ Wn,
                                             u16* __restrict__ out, int n) {
  const int lane = threadIdx.x & 63;
  const int w = threadIdx.x >> 6;
  const float bl = bias[lane];
  const int ngroups = (n + 3) >> 2;
  const int nwaves = gridDim.x * 4;

  for (int grp = blockIdx.x * 4 + w; grp < ngroups; grp += nwaves) {
    const int v0 = grp * 4;
    const int c1 = (v0 + 1 < n) ? v0 + 1 : n;
    const int c2 = (v0 + 2 < n) ? v0 + 2 : n;
    const int c3 = (v0 + 3 < n) ? v0 + 3 : n;
    const int b0 = offs[v0], b1 = offs[c1], b2 = offs[c2], b3 = offs[c3];
    const int b4 = offs[(v0 + 4 < n) ? v0 + 4 : n];

    float d0 = dinv[v0];
    float d1 = dinv[(c1 < n) ? c1 : v0];
    float d2 = dinv[(c2 < n) ? c2 : v0];
    float d3 = dinv[(c3 < n) ? c3 : v0];
    float acc0 = fmaf(bf2f((u32)xw[(size_t)v0 * 64 + lane]), d0 * d0, bl);
    float acc1 = (c1 < n) ? fmaf(bf2f((u32)xw[(size_t)c1 * 64 + lane]), d1 * d1, bl) : 0.f;
    float acc2 = (c2 < n) ? fmaf(bf2f((u32)xw[(size_t)c2 * 64 + lane]), d2 * d2, bl) : 0.f;
    float acc3 = (c3 < n) ? fmaf(bf2f((u32)xw[(size_t)c3 * 64 + lane]), d3 * d3, bl) : 0.f;

    int e = b0;
    int pos = b0;
    while (e < b4) {
      int cnt = b4 - e;
      cnt = (cnt < 64) ? cnt : 64;
      int cex, cey;
      {
        int2 ce = make_int2(0, 0);
        if (lane < cnt) ce = csr[e + lane];
        cex = ce.x; cey = ce.y;
      }
      const int chunk_end = e + cnt;
      AGG_NODE(acc0, b1)
      AGG_NODE(acc1, b2)
      AGG_NODE(acc2, b3)
      AGG_NODE(acc3, b4)
      e = chunk_end;
    }

    float h0 = fmaxf(acc0, 0.f), h1 = fmaxf(acc1, 0.f);
    float h2 = fmaxf(acc2, 0.f), h3 = fmaxf(acc3, 0.f);
    if constexpr (FINAL) {
      out[(size_t)v0 * 64 + lane] = f2bf(h0);
      if (c1 < n) out[(size_t)c1 * 64 + lane] = f2bf(h1);
      if (c2 < n) out[(size_t)c2 * 64 + lane] = f2bf(h2);
      if (c3 < n) out[(size_t)c3 * 64 + lane] = f2bf(h3);
    } else {
      const int hb0 = __float_as_int(h0), hb1 = __float_as_int(h1);
      const int hb2 = __float_as_int(h2), hb3 = __float_as_int(h3);
      float o0 = 0.f, o1 = 0.f, o2 = 0.f, o3 = 0.f;
      #pragma unroll
      for (int k = 0; k < 64; ++k) {
        float wk = Wn[k * 64 + lane];
        o0 = fmaf(__int_as_float(__builtin_amdgcn_readlane(hb0, k)), wk, o0);
        o1 = fmaf(__int_as_float(__builtin_amdgcn_readlane(hb1, k)), wk, o1);
        o2 = fmaf(__int_as_float(__builtin_amdgcn_readlane(hb2, k)), wk, o2);
        o3 = fmaf(__int_as_float(__builtin_amdgcn_readlane(hb3, k)), wk, o3);
      }
      out[(size_t)v0 * 64 + lane] = f2bf(o0);
      if (c1 < n) out[(size_t)c1 * 64 + lane] = f2bf(o1);
      if (c2 < n) out[(size_t)c2 * 64 + lane] = f2bf(o2);
      if (c3 < n) out[(size_t)c3 * 64 + lane] = f2bf(o3);
    }
  }
}

// ---------------- pooling + MLP head + sigmoid ----------------
__global__ __launch_bounds__(256) void k_pool(const u16* __restrict__ x, const int* __restrict__ batch, int n,
                                              const float* __restrict__ Wf1, const float* __restrict__ bf1,
                                              const float* __restrict__ Wf2, const float* __restrict__ bf2,
                                              float* __restrict__ out) {
  int g = blockIdx.x;
  int tid = threadIdx.x, lane = tid & 63, w = tid >> 6;
  int a = 0, b = n;
  while (a < b) { int m = (a + b) >> 1; if (batch[m] < g) a = m + 1; else b = m; }
  int lo = a;
  b = n;
  while (a < b) { int m = (a + b) >> 1; if (batch[m] < g + 1) a = m + 1; else b = m; }
  int hi = a;

  float acc = 0.f;
  for (int r = lo + w; r < hi; r += 4) acc += bf2f((u32)x[(size_t)r * 64 + lane]);
  __shared__ float red[4][64];
  __shared__ float mean[64];
  red[w][lane] = acc;
  __syncthreads();
  if (w == 0) {
    float s = red[0][lane] + red[1][lane] + red[2][lane] + red[3][lane];
    mean[lane] = s / fmaxf((float)(hi - lo), 1.0f);
  }
  __syncthreads();
  if (w == 0) {
    float h = bf1[lane];
    #pragma unroll
    for (int k = 0; k < 64; ++k) h = fmaf(mean[k], Wf1[k * 64 + lane], h);
    h = fmaxf(h, 0.f);
    float vv = h * Wf2[lane];
    for (int off = 32; off > 0; off >>= 1) vv += __shfl_down(vv, off, 64);
    if (lane == 0) out[g] = 1.0f / (1.0f + expf(-(vv + bf2[0])));
  }
}

static inline char* align256(char* p) {
  return (char*)(((uintptr_t)p + 255) & ~(uintptr_t)255);
}

extern "C" void kernel_launch(void* const* d_in, const int* in_sizes, int n_in,
                              void* d_out, int out_size, void* d_ws, size_t ws_size,
                              hipStream_t stream) {
  const int*   x_ids = (const int*)d_in[0];
  const int*   edge  = (const int*)d_in[1];
  const int*   batch = (const int*)d_in[2];
  const float* emb   = (const float*)d_in[3];
  const float* W1    = (const float*)d_in[4];
  const float* b1    = (const float*)d_in[5];
  const float* W2    = (const float*)d_in[6];
  const float* b2    = (const float*)d_in[7];
  const float* W3    = (const float*)d_in[8];
  const float* b3    = (const float*)d_in[9];
  const float* Wf1   = (const float*)d_in[10];
  const float* bf1   = (const float*)d_in[11];
  const float* Wf2   = (const float*)d_in[12];
  const float* bf2   = (const float*)d_in[13];
  float* out = (float*)d_out;

  const int N = in_sizes[0];
  const int E = in_sizes[1] / 2;
  const int G = out_size;
  const int* e_src = edge;
  const int* e_dst = edge + E;

  // workspace layout (bf16 feature buffers)
  char* p = (char*)d_ws;
  u16*   bufA = (u16*)p;              p = align256(p + (size_t)N * 64 * 2);
  u16*   bufB = (u16*)p;              p = align256(p + (size_t)N * 64 * 2);
  int2*  csr  = (int2*)p;             p = align256(p + (size_t)(E + 64) * 8);
  float* dinv = (float*)p;            p = align256(p + (size_t)N * 4);
  int*   cnt  = (int*)p;              p = align256(p + (size_t)N * 4);
  int*   cur  = (int*)p;              p = align256(p + (size_t)N * 4);
  int*   offs = (int*)p;              p = align256(p + (size_t)(N + 1) * 4);
  int*   bsum = (int*)p;              p = align256(p + (size_t)1024 * 4);
  (void)ws_size; (void)n_in;

  const int nb_scan = (N + 1023) / 1024;  // 98 for N=100000 (<=128)
  dim3 blk(256);

  // CSR build (6 launches)
  k_zero<<<dim3(256), blk, 0, stream>>>(cnt, N);
  k_count<<<dim3((E + 255) / 256), blk, 0, stream>>>(e_dst, cnt, E);
  k_scan1<<<dim3(nb_scan), blk, 0, stream>>>(cnt, N, bsum);
  k_scan2<<<dim3(1), dim3(128), 0, stream>>>(bsum, nb_scan, offs + N);
  k_scan3<<<dim3(nb_scan), blk, 0, stream>>>(cnt, N, bsum, offs, cur, dinv);
  k_scatter<<<dim3((E + 255) / 256), blk, 0, stream>>>(e_src, e_dst, dinv, cur, csr, E);

  // layer 1 GEMM: 1 wave per 64 rows, single gather pass
  k_mm1<<<dim3((N + 63) / 64), dim3(64), 0, stream>>>(x_ids, emb, W1, bufA, N);
  // fused conv+next-GEMM chain (4 nodes/wave, grid-stride)
  k_agg<false><<<dim3(2048), blk, 0, stream>>>(bufA, csr, offs, dinv, b1, W2, bufB, N);
  k_agg<false><<<dim3(2048), blk, 0, stream>>>(bufB, csr, offs, dinv, b2, W3, bufA, N);
  k_agg<true><<<dim3(2048), blk, 0, stream>>>(bufA, csr, offs, dinv, b3, nullptr, bufB, N);

  // pool + MLP head
  k_pool<<<dim3(G), blk, 0, stream>>>(bufB, batch, N, Wf1, bf1, Wf2, bf2, out);
}

// Round 9
// 469.613 us; speedup vs baseline: 1.9811x; 1.1519x over previous
//
#include <hip/hip_runtime.h>
#include <hip/hip_bf16.h>

// GCN, bf16 node features + fp32 accumulation.
//  CSR build with segments PADDED to multiples of 8 (dummy edges: src=0, coef=0)
//  k_mm1 (lane=row, acc[64], scalar W, single gather pass)
//  3x k_agg<FINAL>: 4 nodes/wave, 64-edge chunks, uniform 8-edge batches
//                   (no tails), fused next-layer GEMM via readlane.
//  k_pool (mean pool + MLP + sigmoid)

typedef unsigned short u16;
typedef unsigned int u32;

__device__ __forceinline__ float bf2f(u32 u) {
  return __uint_as_float(u << 16);
}
__device__ __forceinline__ u16 f2bf(float f) {
  u32 x = __float_as_uint(f);
  return (u16)((x + 0x7fffu + ((x >> 16) & 1u)) >> 16);  // RNE
}

// ---------------- CSR build ----------------
__global__ __launch_bounds__(256) void k_zero(int* __restrict__ p, long long n) {
  long long i = (long long)blockIdx.x * blockDim.x + threadIdx.x;
  long long stride = (long long)gridDim.x * blockDim.x;
  for (; i < n; i += stride) p[i] = 0;
}

__global__ __launch_bounds__(256) void k_count(const int* __restrict__ dst, int* __restrict__ cnt, int e_count) {
  int e = blockIdx.x * blockDim.x + threadIdx.x;
  if (e < e_count) atomicAdd(&cnt[dst[e]], 1);
}

// scan over PADDED counts ((c+7)&~7)
__global__ __launch_bounds__(256) void k_scan1(const int* __restrict__ cnt, int n, int* __restrict__ bsum) {
  __shared__ int s[256];
  int b = blockIdx.x, t = threadIdx.x;
  int base = b * 1024;
  int sum = 0;
  #pragma unroll
  for (int i = 0; i < 4; ++i) {
    int idx = base + t + i * 256;
    if (idx < n) sum += (cnt[idx] + 7) & ~7;
  }
  s[t] = sum; __syncthreads();
  for (int off = 128; off > 0; off >>= 1) {
    if (t < off) s[t] += s[t + off];
    __syncthreads();
  }
  if (t == 0) bsum[b] = s[0];
}

__global__ __launch_bounds__(128) void k_scan2(int* __restrict__ bsum, int nb, int* __restrict__ total_out) {
  __shared__ int sh[128];
  int t = threadIdx.x;
  sh[t] = (t < nb) ? bsum[t] : 0;
  __syncthreads();
  for (int off = 1; off < 128; off <<= 1) {
    int x = sh[t];
    int y = (t >= off) ? sh[t - off] : 0;
    __syncthreads();
    sh[t] = x + y;
    __syncthreads();
  }
  if (t < nb) bsum[t] = (t == 0) ? 0 : sh[t - 1];
  if (t == 0) *total_out = sh[127];
}

// scan3: padded offsets + cursor copy + dinv (from REAL counts).
__global__ __launch_bounds__(256) void k_scan3(const int* __restrict__ cnt, int n,
                                               const int* __restrict__ bsum_ex, int* __restrict__ offsets,
                                               int* __restrict__ cur, float* __restrict__ dinv) {
  __shared__ int sh[256];
  int b = blockIdx.x, t = threadIdx.x;
  int base = b * 1024 + t * 4;
  int c0 = (base + 0 < n) ? cnt[base + 0] : 0;
  int c1 = (base + 1 < n) ? cnt[base + 1] : 0;
  int c2 = (base + 2 < n) ? cnt[base + 2] : 0;
  int c3 = (base + 3 < n) ? cnt[base + 3] : 0;
  if (base + 0 < n) dinv[base + 0] = rsqrtf((float)c0 + 1.0f);
  if (base + 1 < n) dinv[base + 1] = rsqrtf((float)c1 + 1.0f);
  if (base + 2 < n) dinv[base + 2] = rsqrtf((float)c2 + 1.0f);
  if (base + 3 < n) dinv[base + 3] = rsqrtf((float)c3 + 1.0f);
  int v0 = (c0 + 7) & ~7, v1 = (c1 + 7) & ~7, v2 = (c2 + 7) & ~7, v3 = (c3 + 7) & ~7;
  sh[t] = v0 + v1 + v2 + v3;
  __syncthreads();
  for (int off = 1; off < 256; off <<= 1) {
    int x = sh[t];
    int y = (t >= off) ? sh[t - off] : 0;
    __syncthreads();
    sh[t] = x + y;
    __syncthreads();
  }
  int run = bsum_ex[b] + ((t == 0) ? 0 : sh[t - 1]);
  if (base + 0 < n) { offsets[base + 0] = run; cur[base + 0] = run; } run += v0;
  if (base + 1 < n) { offsets[base + 1] = run; cur[base + 1] = run; } run += v1;
  if (base + 2 < n) { offsets[base + 2] = run; cur[base + 2] = run; } run += v2;
  if (base + 3 < n) { offsets[base + 3] = run; cur[base + 3] = run; }
}

__global__ __launch_bounds__(256) void k_scatter(const int* __restrict__ src, const int* __restrict__ dst,
                                                 const float* __restrict__ dinv,
                                                 int* __restrict__ cursor, int2* __restrict__ csr, int e_count) {
  int e = blockIdx.x * blockDim.x + threadIdx.x;
  if (e >= e_count) return;
  int s = src[e], d = dst[e];
  int pos = atomicAdd(&cursor[d], 1);
  csr[pos] = make_int2(s, __float_as_int(dinv[s] * dinv[d]));
}

// ---------------- layer-1 GEMM: out[r][j] = sum_k emb[ids[r]][k] * W1[k][j] ----------------
// lane = row, 1 wave/block, acc[64]; W loads lane-invariant -> scalarized.
__global__ __launch_bounds__(64, 4) void k_mm1(const int* __restrict__ ids,
                                               const float* __restrict__ emb,
                                               const float* __restrict__ W1,
                                               u16* __restrict__ out, int n) {
  const int lane = threadIdx.x;
  const int r = blockIdx.x * 64 + lane;
  const int rid = ids[(r < n) ? r : (n - 1)];
  const float4* __restrict__ xrow = reinterpret_cast<const float4*>(emb + (size_t)rid * 128);

  float acc[64];
  #pragma unroll
  for (int j = 0; j < 64; ++j) acc[j] = 0.f;

  #pragma unroll 1
  for (int s = 0; s < 4; ++s) {
    float4 xb[8];
    #pragma unroll
    for (int i = 0; i < 8; ++i) xb[i] = xrow[s * 8 + i];
    const float* __restrict__ wbase = W1 + (size_t)(s * 32) * 64;
    #pragma unroll
    for (int i = 0; i < 8; ++i) {
      const float* __restrict__ w0 = wbase + (i * 4) * 64;
      #pragma unroll
      for (int j = 0; j < 64; ++j) {
        acc[j] = fmaf(xb[i].x, w0[j], acc[j]);
        acc[j] = fmaf(xb[i].y, w0[64 + j], acc[j]);
        acc[j] = fmaf(xb[i].z, w0[128 + j], acc[j]);
        acc[j] = fmaf(xb[i].w, w0[192 + j], acc[j]);
      }
    }
  }

  if (r < n) {
    u16* op = out + (size_t)r * 64;
    #pragma unroll
    for (int q = 0; q < 8; ++q) {
      uint2 pk;
      pk.x = ((u32)f2bf(acc[q * 4 + 1]) << 16) | f2bf(acc[q * 4 + 0]);
      pk.y = ((u32)f2bf(acc[q * 4 + 3]) << 16) | f2bf(acc[q * 4 + 2]);
      *reinterpret_cast<uint2*>(op + q * 4) = pk;
    }
  }
}

// ---------------- fused aggregation + next-layer GEMM ----------------
// Segments padded to x8: every 8-batch belongs to exactly ONE node. Per batch:
// 8 independent gathers -> 8 FMAs into tmp -> one wave-uniform branch add.

template <bool FINAL>
__global__ __launch_bounds__(256) void k_agg(const u16* __restrict__ xw, const int2* __restrict__ csr,
                                             const int* __restrict__ offs, const float* __restrict__ dinv,
                                             const float* __restrict__ bias, const float* __restrict__ Wn,
                                             u16* __restrict__ out, int n) {
  const int lane = threadIdx.x & 63;
  const int w = threadIdx.x >> 6;
  const float bl = bias[lane];
  const int ngroups = (n + 3) >> 2;
  const int nwaves = gridDim.x * 4;

  for (int grp = blockIdx.x * 4 + w; grp < ngroups; grp += nwaves) {
    const int v0 = grp * 4;
    const int c1 = (v0 + 1 < n) ? v0 + 1 : n;
    const int c2 = (v0 + 2 < n) ? v0 + 2 : n;
    const int c3 = (v0 + 3 < n) ? v0 + 3 : n;
    const int b0 = offs[v0], b1 = offs[c1], b2 = offs[c2], b3 = offs[c3];
    const int b4 = offs[(v0 + 4 < n) ? v0 + 4 : n];

    float d0 = dinv[v0];
    float d1 = dinv[(c1 < n) ? c1 : v0];
    float d2 = dinv[(c2 < n) ? c2 : v0];
    float d3 = dinv[(c3 < n) ? c3 : v0];
    float acc0 = fmaf(bf2f((u32)xw[(size_t)v0 * 64 + lane]), d0 * d0, bl);
    float acc1 = (c1 < n) ? fmaf(bf2f((u32)xw[(size_t)c1 * 64 + lane]), d1 * d1, bl) : 0.f;
    float acc2 = (c2 < n) ? fmaf(bf2f((u32)xw[(size_t)c2 * 64 + lane]), d2 * d2, bl) : 0.f;
    float acc3 = (c3 < n) ? fmaf(bf2f((u32)xw[(size_t)c3 * 64 + lane]), d3 * d3, bl) : 0.f;

    int e = b0;
    while (e < b4) {
      int cnt = b4 - e;
      cnt = (cnt < 64) ? cnt : 64;
      int cex, cey;
      {
        int2 ce = make_int2(0, 0);
        if (lane < cnt) ce = csr[e + lane];
        cex = ce.x; cey = ce.y;
      }
      // uniform 8-edge batches; each batch maps to exactly one node
      for (int bs = 0; bs < cnt; bs += 8) {
        float vv[8];
        #pragma unroll
        for (int t = 0; t < 8; ++t) {
          int sb = __builtin_amdgcn_readlane(cex, bs + t);
          vv[t] = bf2f((u32)xw[(size_t)sb * 64 + lane]);
        }
        float tmp = 0.f;
        #pragma unroll
        for (int t = 0; t < 8; ++t) {
          float cf = __int_as_float(__builtin_amdgcn_readlane(cey, bs + t));
          tmp = fmaf(vv[t], cf, tmp);
        }
        const int ep = e + bs;  // wave-uniform
        if (ep < b1) acc0 += tmp;
        else if (ep < b2) acc1 += tmp;
        else if (ep < b3) acc2 += tmp;
        else acc3 += tmp;
      }
      e += cnt;
    }

    float h0 = fmaxf(acc0, 0.f), h1 = fmaxf(acc1, 0.f);
    float h2 = fmaxf(acc2, 0.f), h3 = fmaxf(acc3, 0.f);
    if constexpr (FINAL) {
      out[(size_t)v0 * 64 + lane] = f2bf(h0);
      if (c1 < n) out[(size_t)c1 * 64 + lane] = f2bf(h1);
      if (c2 < n) out[(size_t)c2 * 64 + lane] = f2bf(h2);
      if (c3 < n) out[(size_t)c3 * 64 + lane] = f2bf(h3);
    } else {
      const int hb0 = __float_as_int(h0), hb1 = __float_as_int(h1);
      const int hb2 = __float_as_int(h2), hb3 = __float_as_int(h3);
      float o0 = 0.f, o1 = 0.f, o2 = 0.f, o3 = 0.f;
      #pragma unroll
      for (int k = 0; k < 64; ++k) {
        float wk = Wn[k * 64 + lane];
        o0 = fmaf(__int_as_float(__builtin_amdgcn_readlane(hb0, k)), wk, o0);
        o1 = fmaf(__int_as_float(__builtin_amdgcn_readlane(hb1, k)), wk, o1);
        o2 = fmaf(__int_as_float(__builtin_amdgcn_readlane(hb2, k)), wk, o2);
        o3 = fmaf(__int_as_float(__builtin_amdgcn_readlane(hb3, k)), wk, o3);
      }
      out[(size_t)v0 * 64 + lane] = f2bf(o0);
      if (c1 < n) out[(size_t)c1 * 64 + lane] = f2bf(o1);
      if (c2 < n) out[(size_t)c2 * 64 + lane] = f2bf(o2);
      if (c3 < n) out[(size_t)c3 * 64 + lane] = f2bf(o3);
    }
  }
}

// ---------------- pooling + MLP head + sigmoid ----------------
__global__ __launch_bounds__(256) void k_pool(const u16* __restrict__ x, const int* __restrict__ batch, int n,
                                              const float* __restrict__ Wf1, const float* __restrict__ bf1,
                                              const float* __restrict__ Wf2, const float* __restrict__ bf2,
                                              float* __restrict__ out) {
  int g = blockIdx.x;
  int tid = threadIdx.x, lane = tid & 63, w = tid >> 6;
  int a = 0, b = n;
  while (a < b) { int m = (a + b) >> 1; if (batch[m] < g) a = m + 1; else b = m; }
  int lo = a;
  b = n;
  while (a < b) { int m = (a + b) >> 1; if (batch[m] < g + 1) a = m + 1; else b = m; }
  int hi = a;

  float acc = 0.f;
  for (int r = lo + w; r < hi; r += 4) acc += bf2f((u32)x[(size_t)r * 64 + lane]);
  __shared__ float red[4][64];
  __shared__ float mean[64];
  red[w][lane] = acc;
  __syncthreads();
  if (w == 0) {
    float s = red[0][lane] + red[1][lane] + red[2][lane] + red[3][lane];
    mean[lane] = s / fmaxf((float)(hi - lo), 1.0f);
  }
  __syncthreads();
  if (w == 0) {
    float h = bf1[lane];
    #pragma unroll
    for (int k = 0; k < 64; ++k) h = fmaf(mean[k], Wf1[k * 64 + lane], h);
    h = fmaxf(h, 0.f);
    float vv = h * Wf2[lane];
    for (int off = 32; off > 0; off >>= 1) vv += __shfl_down(vv, off, 64);
    if (lane == 0) out[g] = 1.0f / (1.0f + expf(-(vv + bf2[0])));
  }
}

static inline char* align256(char* p) {
  return (char*)(((uintptr_t)p + 255) & ~(uintptr_t)255);
}

extern "C" void kernel_launch(void* const* d_in, const int* in_sizes, int n_in,
                              void* d_out, int out_size, void* d_ws, size_t ws_size,
                              hipStream_t stream) {
  const int*   x_ids = (const int*)d_in[0];
  const int*   edge  = (const int*)d_in[1];
  const int*   batch = (const int*)d_in[2];
  const float* emb   = (const float*)d_in[3];
  const float* W1    = (const float*)d_in[4];
  const float* b1    = (const float*)d_in[5];
  const float* W2    = (const float*)d_in[6];
  const float* b2    = (const float*)d_in[7];
  const float* W3    = (const float*)d_in[8];
  const float* b3    = (const float*)d_in[9];
  const float* Wf1   = (const float*)d_in[10];
  const float* bf1   = (const float*)d_in[11];
  const float* Wf2   = (const float*)d_in[12];
  const float* bf2   = (const float*)d_in[13];
  float* out = (float*)d_out;

  const int N = in_sizes[0];
  const int E = in_sizes[1] / 2;
  const int G = out_size;
  const int* e_src = edge;
  const int* e_dst = edge + E;

  const size_t EPAD = (size_t)E + 8 * (size_t)((N + 1)) + 64;  // padded csr capacity

  // workspace layout (bf16 feature buffers)
  char* p = (char*)d_ws;
  u16*   bufA = (u16*)p;              p = align256(p + (size_t)N * 64 * 2);
  u16*   bufB = (u16*)p;              p = align256(p + (size_t)N * 64 * 2);
  int2*  csr  = (int2*)p;             p = align256(p + EPAD * 8);
  float* dinv = (float*)p;            p = align256(p + (size_t)N * 4);
  int*   cnt  = (int*)p;              p = align256(p + (size_t)N * 4);
  int*   cur  = (int*)p;              p = align256(p + (size_t)N * 4);
  int*   offs = (int*)p;              p = align256(p + (size_t)(N + 1) * 4);
  int*   bsum = (int*)p;              p = align256(p + (size_t)1024 * 4);
  (void)ws_size; (void)n_in;

  const int nb_scan = (N + 1023) / 1024;  // 98 for N=100000 (<=128)
  dim3 blk(256);

  // CSR build (7 launches; csr pre-zeroed so padding slots are {src=0, coef=0})
  k_zero<<<dim3(2048), blk, 0, stream>>>((int*)csr, (long long)EPAD * 2);
  k_zero<<<dim3(256), blk, 0, stream>>>(cnt, N);
  k_count<<<dim3((E + 255) / 256), blk, 0, stream>>>(e_dst, cnt, E);
  k_scan1<<<dim3(nb_scan), blk, 0, stream>>>(cnt, N, bsum);
  k_scan2<<<dim3(1), dim3(128), 0, stream>>>(bsum, nb_scan, offs + N);
  k_scan3<<<dim3(nb_scan), blk, 0, stream>>>(cnt, N, bsum, offs, cur, dinv);
  k_scatter<<<dim3((E + 255) / 256), blk, 0, stream>>>(e_src, e_dst, dinv, cur, csr, E);

  // layer 1 GEMM: 1 wave per 64 rows
  k_mm1<<<dim3((N + 63) / 64), dim3(64), 0, stream>>>(x_ids, emb, W1, bufA, N);
  // fused conv+next-GEMM chain (4 nodes/wave, grid-stride)
  k_agg<false><<<dim3(2048), blk, 0, stream>>>(bufA, csr, offs, dinv, b1, W2, bufB, N);
  k_agg<false><<<dim3(2048), blk, 0, stream>>>(bufB, csr, offs, dinv, b2, W3, bufA, N);
  k_agg<true><<<dim3(2048), blk, 0, stream>>>(bufA, csr, offs, dinv, b3, nullptr, bufB, N);

  // pool + MLP head
  k_pool<<<dim3(G), blk, 0, stream>>>(bufB, batch, N, Wf1, bf1, Wf2, bf2, out);
}

// Round 11
// 440.428 us; speedup vs baseline: 2.1124x; 1.0663x over previous
//
#include <hip/hip_runtime.h>
#include <hip/hip_bf16.h>

// GCN, bf16 node features + fp32 accumulation.
//  CSR build: count captures per-edge rank (atomic return) -> scatter is
//  atomic-free (pos = offs[dst] + rank). Segments padded to x8.
//  k_mm1 (lane=row, acc[64], scalar W); 3x k_agg (uniform 8-batches, fused W);
//  k_pool (mean pool + MLP + sigmoid)

typedef unsigned short u16;
typedef unsigned int u32;
typedef unsigned long long u64;

__device__ __forceinline__ float bf2f(u32 u) {
  return __uint_as_float(u << 16);
}
__device__ __forceinline__ u16 f2bf(float f) {
  u32 x = __float_as_uint(f);
  return (u16)((x + 0x7fffu + ((x >> 16) & 1u)) >> 16);  // RNE
}

// ---------------- CSR build ----------------
__global__ __launch_bounds__(256) void k_zero(int* __restrict__ p, long long n) {
  long long i = (long long)blockIdx.x * blockDim.x + threadIdx.x;
  long long stride = (long long)gridDim.x * blockDim.x;
  for (; i < n; i += stride) p[i] = 0;
}

__global__ __launch_bounds__(256) void k_zero4(int4* __restrict__ p, long long n4) {
  long long i = (long long)blockIdx.x * blockDim.x + threadIdx.x;
  long long stride = (long long)gridDim.x * blockDim.x;
  int4 z = make_int4(0, 0, 0, 0);
  for (; i < n4; i += stride) p[i] = z;
}

// count in-degree AND record each edge's arrival rank (atomic return value).
__global__ __launch_bounds__(256) void k_count_rank(const int* __restrict__ dst, int* __restrict__ cnt,
                                                    int* __restrict__ rank, int e_count) {
  int e = blockIdx.x * blockDim.x + threadIdx.x;
  if (e < e_count) rank[e] = atomicAdd(&cnt[dst[e]], 1);
}

// scan over PADDED counts ((c+7)&~7)
__global__ __launch_bounds__(256) void k_scan1(const int* __restrict__ cnt, int n, int* __restrict__ bsum) {
  __shared__ int s[256];
  int b = blockIdx.x, t = threadIdx.x;
  int base = b * 1024;
  int sum = 0;
  #pragma unroll
  for (int i = 0; i < 4; ++i) {
    int idx = base + t + i * 256;
    if (idx < n) sum += (cnt[idx] + 7) & ~7;
  }
  s[t] = sum; __syncthreads();
  for (int off = 128; off > 0; off >>= 1) {
    if (t < off) s[t] += s[t + off];
    __syncthreads();
  }
  if (t == 0) bsum[b] = s[0];
}

__global__ __launch_bounds__(128) void k_scan2(int* __restrict__ bsum, int nb, int* __restrict__ total_out) {
  __shared__ int sh[128];
  int t = threadIdx.x;
  sh[t] = (t < nb) ? bsum[t] : 0;
  __syncthreads();
  for (int off = 1; off < 128; off <<= 1) {
    int x = sh[t];
    int y = (t >= off) ? sh[t - off] : 0;
    __syncthreads();
    sh[t] = x + y;
    __syncthreads();
  }
  if (t < nb) bsum[t] = (t == 0) ? 0 : sh[t - 1];
  if (t == 0) *total_out = sh[127];
}

// scan3: padded offsets + dinv (from REAL counts).
__global__ __launch_bounds__(256) void k_scan3(const int* __restrict__ cnt, int n,
                                               const int* __restrict__ bsum_ex, int* __restrict__ offsets,
                                               float* __restrict__ dinv) {
  __shared__ int sh[256];
  int b = blockIdx.x, t = threadIdx.x;
  int base = b * 1024 + t * 4;
  int c0 = (base + 0 < n) ? cnt[base + 0] : 0;
  int c1 = (base + 1 < n) ? cnt[base + 1] : 0;
  int c2 = (base + 2 < n) ? cnt[base + 2] : 0;
  int c3 = (base + 3 < n) ? cnt[base + 3] : 0;
  if (base + 0 < n) dinv[base + 0] = rsqrtf((float)c0 + 1.0f);
  if (base + 1 < n) dinv[base + 1] = rsqrtf((float)c1 + 1.0f);
  if (base + 2 < n) dinv[base + 2] = rsqrtf((float)c2 + 1.0f);
  if (base + 3 < n) dinv[base + 3] = rsqrtf((float)c3 + 1.0f);
  int v0 = (c0 + 7) & ~7, v1 = (c1 + 7) & ~7, v2 = (c2 + 7) & ~7, v3 = (c3 + 7) & ~7;
  sh[t] = v0 + v1 + v2 + v3;
  __syncthreads();
  for (int off = 1; off < 256; off <<= 1) {
    int x = sh[t];
    int y = (t >= off) ? sh[t - off] : 0;
    __syncthreads();
    sh[t] = x + y;
    __syncthreads();
  }
  int run = bsum_ex[b] + ((t == 0) ? 0 : sh[t - 1]);
  if (base + 0 < n) offsets[base + 0] = run; run += v0;
  if (base + 1 < n) offsets[base + 1] = run; run += v1;
  if (base + 2 < n) offsets[base + 2] = run; run += v2;
  if (base + 3 < n) offsets[base + 3] = run;
}

// atomic-free scatter: pos = offs[dst] + rank; packed 8B nontemporal store.
__global__ __launch_bounds__(256) void k_scatter(const int* __restrict__ src, const int* __restrict__ dst,
                                                 const int* __restrict__ rank,
                                                 const float* __restrict__ dinv,
                                                 const int* __restrict__ offs,
                                                 long long* __restrict__ csr, int e_count) {
  int e = blockIdx.x * blockDim.x + threadIdx.x;
  if (e >= e_count) return;
  int s = src[e], d = dst[e];
  int pos = offs[d] + rank[e];
  u64 val = (u64)(u32)s | ((u64)(u32)__float_as_uint(dinv[s] * dinv[d]) << 32);
  __builtin_nontemporal_store((long long)val, &csr[pos]);
}

// ---------------- layer-1 GEMM: out[r][j] = sum_k emb[ids[r]][k] * W1[k][j] ----------------
// lane = row, 1 wave/block, acc[64]; W loads lane-invariant -> scalarized.
__global__ __launch_bounds__(64, 4) void k_mm1(const int* __restrict__ ids,
                                               const float* __restrict__ emb,
                                               const float* __restrict__ W1,
                                               u16* __restrict__ out, int n) {
  const int lane = threadIdx.x;
  const int r = blockIdx.x * 64 + lane;
  const int rid = ids[(r < n) ? r : (n - 1)];
  const float4* __restrict__ xrow = reinterpret_cast<const float4*>(emb + (size_t)rid * 128);

  float acc[64];
  #pragma unroll
  for (int j = 0; j < 64; ++j) acc[j] = 0.f;

  #pragma unroll 1
  for (int s = 0; s < 4; ++s) {
    float4 xb[8];
    #pragma unroll
    for (int i = 0; i < 8; ++i) xb[i] = xrow[s * 8 + i];
    const float* __restrict__ wbase = W1 + (size_t)(s * 32) * 64;
    #pragma unroll
    for (int i = 0; i < 8; ++i) {
      const float* __restrict__ w0 = wbase + (i * 4) * 64;
      #pragma unroll
      for (int j = 0; j < 64; ++j) {
        acc[j] = fmaf(xb[i].x, w0[j], acc[j]);
        acc[j] = fmaf(xb[i].y, w0[64 + j], acc[j]);
        acc[j] = fmaf(xb[i].z, w0[128 + j], acc[j]);
        acc[j] = fmaf(xb[i].w, w0[192 + j], acc[j]);
      }
    }
  }

  if (r < n) {
    u16* op = out + (size_t)r * 64;
    #pragma unroll
    for (int q = 0; q < 8; ++q) {
      uint2 pk;
      pk.x = ((u32)f2bf(acc[q * 4 + 1]) << 16) | f2bf(acc[q * 4 + 0]);
      pk.y = ((u32)f2bf(acc[q * 4 + 3]) << 16) | f2bf(acc[q * 4 + 2]);
      *reinterpret_cast<uint2*>(op + q * 4) = pk;
    }
  }
}

// ---------------- fused aggregation + next-layer GEMM ----------------
// Segments padded to x8: every 8-batch belongs to exactly ONE node. Per batch:
// 8 independent gathers -> 8 FMAs into tmp -> one wave-uniform branch add.

template <bool FINAL>
__global__ __launch_bounds__(256) void k_agg(const u16* __restrict__ xw, const int2* __restrict__ csr,
                                             const int* __restrict__ offs, const float* __restrict__ dinv,
                                             const float* __restrict__ bias, const float* __restrict__ Wn,
                                             u16* __restrict__ out, int n) {
  const int lane = threadIdx.x & 63;
  const int w = threadIdx.x >> 6;
  const float bl = bias[lane];
  const int ngroups = (n + 3) >> 2;
  const int nwaves = gridDim.x * 4;

  for (int grp = blockIdx.x * 4 + w; grp < ngroups; grp += nwaves) {
    const int v0 = grp * 4;
    const int c1 = (v0 + 1 < n) ? v0 + 1 : n;
    const int c2 = (v0 + 2 < n) ? v0 + 2 : n;
    const int c3 = (v0 + 3 < n) ? v0 + 3 : n;
    const int b0 = offs[v0], b1 = offs[c1], b2 = offs[c2], b3 = offs[c3];
    const int b4 = offs[(v0 + 4 < n) ? v0 + 4 : n];

    float d0 = dinv[v0];
    float d1 = dinv[(c1 < n) ? c1 : v0];
    float d2 = dinv[(c2 < n) ? c2 : v0];
    float d3 = dinv[(c3 < n) ? c3 : v0];
    float acc0 = fmaf(bf2f((u32)xw[(size_t)v0 * 64 + lane]), d0 * d0, bl);
    float acc1 = (c1 < n) ? fmaf(bf2f((u32)xw[(size_t)c1 * 64 + lane]), d1 * d1, bl) : 0.f;
    float acc2 = (c2 < n) ? fmaf(bf2f((u32)xw[(size_t)c2 * 64 + lane]), d2 * d2, bl) : 0.f;
    float acc3 = (c3 < n) ? fmaf(bf2f((u32)xw[(size_t)c3 * 64 + lane]), d3 * d3, bl) : 0.f;

    int e = b0;
    while (e < b4) {
      int cnt = b4 - e;
      cnt = (cnt < 64) ? cnt : 64;
      int cex, cey;
      {
        int2 ce = make_int2(0, 0);
        if (lane < cnt) ce = csr[e + lane];
        cex = ce.x; cey = ce.y;
      }
      // uniform 8-edge batches; each batch maps to exactly one node
      for (int bs = 0; bs < cnt; bs += 8) {
        float vv[8];
        #pragma unroll
        for (int t = 0; t < 8; ++t) {
          int sb = __builtin_amdgcn_readlane(cex, bs + t);
          vv[t] = bf2f((u32)xw[(size_t)sb * 64 + lane]);
        }
        float tmp = 0.f;
        #pragma unroll
        for (int t = 0; t < 8; ++t) {
          float cf = __int_as_float(__builtin_amdgcn_readlane(cey, bs + t));
          tmp = fmaf(vv[t], cf, tmp);
        }
        const int ep = e + bs;  // wave-uniform
        if (ep < b1) acc0 += tmp;
        else if (ep < b2) acc1 += tmp;
        else if (ep < b3) acc2 += tmp;
        else acc3 += tmp;
      }
      e += cnt;
    }

    float h0 = fmaxf(acc0, 0.f), h1 = fmaxf(acc1, 0.f);
    float h2 = fmaxf(acc2, 0.f), h3 = fmaxf(acc3, 0.f);
    if constexpr (FINAL) {
      out[(size_t)v0 * 64 + lane] = f2bf(h0);
      if (c1 < n) out[(size_t)c1 * 64 + lane] = f2bf(h1);
      if (c2 < n) out[(size_t)c2 * 64 + lane] = f2bf(h2);
      if (c3 < n) out[(size_t)c3 * 64 + lane] = f2bf(h3);
    } else {
      const int hb0 = __float_as_int(h0), hb1 = __float_as_int(h1);
      const int hb2 = __float_as_int(h2), hb3 = __float_as_int(h3);
      float o0 = 0.f, o1 = 0.f, o2 = 0.f, o3 = 0.f;
      #pragma unroll
      for (int k = 0; k < 64; ++k) {
        float wk = Wn[k * 64 + lane];
        o0 = fmaf(__int_as_float(__builtin_amdgcn_readlane(hb0, k)), wk, o0);
        o1 = fmaf(__int_as_float(__builtin_amdgcn_readlane(hb1, k)), wk, o1);
        o2 = fmaf(__int_as_float(__builtin_amdgcn_readlane(hb2, k)), wk, o2);
        o3 = fmaf(__int_as_float(__builtin_amdgcn_readlane(hb3, k)), wk, o3);
      }
      out[(size_t)v0 * 64 + lane] = f2bf(o0);
      if (c1 < n) out[(size_t)c1 * 64 + lane] = f2bf(o1);
      if (c2 < n) out[(size_t)c2 * 64 + lane] = f2bf(o2);
      if (c3 < n) out[(size_t)c3 * 64 + lane] = f2bf(o3);
    }
  }
}

// ---------------- pooling + MLP head + sigmoid ----------------
__global__ __launch_bounds__(256) void k_pool(const u16* __restrict__ x, const int* __restrict__ batch, int n,
                                              const float* __restrict__ Wf1, const float* __restrict__ bf1,
                                              const float* __restrict__ Wf2, const float* __restrict__ bf2,
                                              float* __restrict__ out) {
  int g = blockIdx.x;
  int tid = threadIdx.x, lane = tid & 63, w = tid >> 6;
  int a = 0, b = n;
  while (a < b) { int m = (a + b) >> 1; if (batch[m] < g) a = m + 1; else b = m; }
  int lo = a;
  b = n;
  while (a < b) { int m = (a + b) >> 1; if (batch[m] < g + 1) a = m + 1; else b = m; }
  int hi = a;

  float acc = 0.f;
  for (int r = lo + w; r < hi; r += 4) acc += bf2f((u32)x[(size_t)r * 64 + lane]);
  __shared__ float red[4][64];
  __shared__ float mean[64];
  red[w][lane] = acc;
  __syncthreads();
  if (w == 0) {
    float s = red[0][lane] + red[1][lane] + red[2][lane] + red[3][lane];
    mean[lane] = s / fmaxf((float)(hi - lo), 1.0f);
  }
  __syncthreads();
  if (w == 0) {
    float h = bf1[lane];
    #pragma unroll
    for (int k = 0; k < 64; ++k) h = fmaf(mean[k], Wf1[k * 64 + lane], h);
    h = fmaxf(h, 0.f);
    float vv = h * Wf2[lane];
    for (int off = 32; off > 0; off >>= 1) vv += __shfl_down(vv, off, 64);
    if (lane == 0) out[g] = 1.0f / (1.0f + expf(-(vv + bf2[0])));
  }
}

static inline char* align256(char* p) {
  return (char*)(((uintptr_t)p + 255) & ~(uintptr_t)255);
}

extern "C" void kernel_launch(void* const* d_in, const int* in_sizes, int n_in,
                              void* d_out, int out_size, void* d_ws, size_t ws_size,
                              hipStream_t stream) {
  const int*   x_ids = (const int*)d_in[0];
  const int*   edge  = (const int*)d_in[1];
  const int*   batch = (const int*)d_in[2];
  const float* emb   = (const float*)d_in[3];
  const float* W1    = (const float*)d_in[4];
  const float* b1    = (const float*)d_in[5];
  const float* W2    = (const float*)d_in[6];
  const float* b2    = (const float*)d_in[7];
  const float* W3    = (const float*)d_in[8];
  const float* b3    = (const float*)d_in[9];
  const float* Wf1   = (const float*)d_in[10];
  const float* bf1   = (const float*)d_in[11];
  const float* Wf2   = (const float*)d_in[12];
  const float* bf2   = (const float*)d_in[13];
  float* out = (float*)d_out;

  const int N = in_sizes[0];
  const int E = in_sizes[1] / 2;
  const int G = out_size;
  const int* e_src = edge;
  const int* e_dst = edge + E;

  const size_t EPAD = (size_t)E + 8 * (size_t)(N + 1) + 64;  // padded csr capacity

  // workspace layout (bf16 feature buffers)
  char* p = (char*)d_ws;
  u16*   bufA = (u16*)p;              p = align256(p + (size_t)N * 64 * 2);
  u16*   bufB = (u16*)p;              p = align256(p + (size_t)N * 64 * 2);
  int2*  csr  = (int2*)p;             p = align256(p + EPAD * 8);
  float* dinv = (float*)p;            p = align256(p + (size_t)N * 4);
  int*   cnt  = (int*)p;              p = align256(p + (size_t)N * 4);
  int*   offs = (int*)p;              p = align256(p + (size_t)(N + 1) * 4);
  int*   bsum = (int*)p;              p = align256(p + (size_t)1024 * 4);
  int*   rank = (int*)bufA;  // aliases bufA: rank lifetime ends before mm1 writes bufA
  (void)ws_size; (void)n_in;

  const int nb_scan = (N + 1023) / 1024;  // 98 for N=100000 (<=128)
  dim3 blk(256);

  // CSR build (csr pre-zeroed so padding slots are {src=0, coef=0})
  k_zero4<<<dim3(1024), blk, 0, stream>>>((int4*)csr, (long long)(EPAD * 2 / 4));
  k_zero<<<dim3(256), blk, 0, stream>>>(cnt, N);
  k_count_rank<<<dim3((E + 255) / 256), blk, 0, stream>>>(e_dst, cnt, rank, E);
  k_scan1<<<dim3(nb_scan), blk, 0, stream>>>(cnt, N, bsum);
  k_scan2<<<dim3(1), dim3(128), 0, stream>>>(bsum, nb_scan, offs + N);
  k_scan3<<<dim3(nb_scan), blk, 0, stream>>>(cnt, N, bsum, offs, dinv);
  k_scatter<<<dim3((E + 255) / 256), blk, 0, stream>>>(e_src, e_dst, rank, dinv, offs, (long long*)csr, E);

  // layer 1 GEMM: 1 wave per 64 rows
  k_mm1<<<dim3((N + 63) / 64), dim3(64), 0, stream>>>(x_ids, emb, W1, bufA, N);
  // fused conv+next-GEMM chain (4 nodes/wave, grid-stride)
  k_agg<false><<<dim3(2048), blk, 0, stream>>>(bufA, csr, offs, dinv, b1, W2, bufB, N);
  k_agg<false><<<dim3(2048), blk, 0, stream>>>(bufB, csr, offs, dinv, b2, W3, bufA, N);
  k_agg<true><<<dim3(2048), blk, 0, stream>>>(bufA, csr, offs, dinv, b3, nullptr, bufB, N);

  // pool + MLP head
  k_pool<<<dim3(G), blk, 0, stream>>>(bufB, batch, N, Wf1, bf1, Wf2, bf2, out);
}

// Round 12
// 399.008 us; speedup vs baseline: 2.3317x; 1.1038x over previous
//
#include <hip/hip_runtime.h>
#include <hip/hip_bf16.h>

// GCN, bf16 node features + fp32 accumulation.
//  CSR build: rank capture -> atomic-free scatter; segments padded to x8.
//  k_mm1_scatter: grid-partitioned fusion of layer-1 GEMM (independent of CSR)
//  with the CSR scatter (latency-bound) -> they overlap on the CUs.
//  3x k_agg (uniform 8-batches, fused next-W GEMM); k_pool.

typedef unsigned short u16;
typedef unsigned int u32;
typedef unsigned long long u64;

__device__ __forceinline__ float bf2f(u32 u) {
  return __uint_as_float(u << 16);
}
__device__ __forceinline__ u16 f2bf(float f) {
  u32 x = __float_as_uint(f);
  return (u16)((x + 0x7fffu + ((x >> 16) & 1u)) >> 16);  // RNE
}

// ---------------- init: zero csr (int4) and cnt in one launch ----------------
__global__ __launch_bounds__(256) void k_init(int4* __restrict__ csr4, long long n4,
                                              int* __restrict__ cnt, int n, int zb) {
  if ((int)blockIdx.x < zb) {
    long long i = (long long)blockIdx.x * blockDim.x + threadIdx.x;
    long long stride = (long long)zb * blockDim.x;
    int4 z = make_int4(0, 0, 0, 0);
    for (; i < n4; i += stride) csr4[i] = z;
  } else {
    int nb = gridDim.x - zb;
    int i = (blockIdx.x - zb) * blockDim.x + threadIdx.x;
    int stride = nb * blockDim.x;
    for (; i < n; i += stride) cnt[i] = 0;
  }
}

// count in-degree AND record each edge's arrival rank (atomic return value).
__global__ __launch_bounds__(256) void k_count_rank(const int* __restrict__ dst, int* __restrict__ cnt,
                                                    int* __restrict__ rank, int e_count) {
  int e = blockIdx.x * blockDim.x + threadIdx.x;
  if (e < e_count) rank[e] = atomicAdd(&cnt[dst[e]], 1);
}

// scan over PADDED counts ((c+7)&~7)
__global__ __launch_bounds__(256) void k_scan1(const int* __restrict__ cnt, int n, int* __restrict__ bsum) {
  __shared__ int s[256];
  int b = blockIdx.x, t = threadIdx.x;
  int base = b * 1024;
  int sum = 0;
  #pragma unroll
  for (int i = 0; i < 4; ++i) {
    int idx = base + t + i * 256;
    if (idx < n) sum += (cnt[idx] + 7) & ~7;
  }
  s[t] = sum; __syncthreads();
  for (int off = 128; off > 0; off >>= 1) {
    if (t < off) s[t] += s[t + off];
    __syncthreads();
  }
  if (t == 0) bsum[b] = s[0];
}

__global__ __launch_bounds__(128) void k_scan2(int* __restrict__ bsum, int nb, int* __restrict__ total_out) {
  __shared__ int sh[128];
  int t = threadIdx.x;
  sh[t] = (t < nb) ? bsum[t] : 0;
  __syncthreads();
  for (int off = 1; off < 128; off <<= 1) {
    int x = sh[t];
    int y = (t >= off) ? sh[t - off] : 0;
    __syncthreads();
    sh[t] = x + y;
    __syncthreads();
  }
  if (t < nb) bsum[t] = (t == 0) ? 0 : sh[t - 1];
  if (t == 0) *total_out = sh[127];
}

// scan3: padded offsets + dinv (from REAL counts).
__global__ __launch_bounds__(256) void k_scan3(const int* __restrict__ cnt, int n,
                                               const int* __restrict__ bsum_ex, int* __restrict__ offsets,
                                               float* __restrict__ dinv) {
  __shared__ int sh[256];
  int b = blockIdx.x, t = threadIdx.x;
  int base = b * 1024 + t * 4;
  int c0 = (base + 0 < n) ? cnt[base + 0] : 0;
  int c1 = (base + 1 < n) ? cnt[base + 1] : 0;
  int c2 = (base + 2 < n) ? cnt[base + 2] : 0;
  int c3 = (base + 3 < n) ? cnt[base + 3] : 0;
  if (base + 0 < n) dinv[base + 0] = rsqrtf((float)c0 + 1.0f);
  if (base + 1 < n) dinv[base + 1] = rsqrtf((float)c1 + 1.0f);
  if (base + 2 < n) dinv[base + 2] = rsqrtf((float)c2 + 1.0f);
  if (base + 3 < n) dinv[base + 3] = rsqrtf((float)c3 + 1.0f);
  int v0 = (c0 + 7) & ~7, v1 = (c1 + 7) & ~7, v2 = (c2 + 7) & ~7, v3 = (c3 + 7) & ~7;
  sh[t] = v0 + v1 + v2 + v3;
  __syncthreads();
  for (int off = 1; off < 256; off <<= 1) {
    int x = sh[t];
    int y = (t >= off) ? sh[t - off] : 0;
    __syncthreads();
    sh[t] = x + y;
    __syncthreads();
  }
  int run = bsum_ex[b] + ((t == 0) ? 0 : sh[t - 1]);
  if (base + 0 < n) offsets[base + 0] = run; run += v0;
  if (base + 1 < n) offsets[base + 1] = run; run += v1;
  if (base + 2 < n) offsets[base + 2] = run; run += v2;
  if (base + 3 < n) offsets[base + 3] = run;
}

// ---------------- fused layer-1 GEMM (blocks [0,mmb)) + scatter (rest) ----------------
// mm1: lane = row, 4 waves/block = 256 rows; acc[64]; W loads lane-invariant.
// scatter: atomic-free, pos = offs[dst] + rank, packed 8B nontemporal store.
__global__ __launch_bounds__(256, 4) void k_mm1_scatter(
    const int* __restrict__ ids, const float* __restrict__ emb,
    const float* __restrict__ W1, u16* __restrict__ out, int n, int mmb,
    const int* __restrict__ src, const int* __restrict__ dst,
    const int* __restrict__ rank, const float* __restrict__ dinv,
    const int* __restrict__ offs, long long* __restrict__ csr, int e_count) {
  if ((int)blockIdx.x >= mmb) {
    int e = (blockIdx.x - mmb) * 256 + threadIdx.x;
    if (e < e_count) {
      int s = src[e], d = dst[e];
      int pos = offs[d] + rank[e];
      u64 val = (u64)(u32)s | ((u64)(u32)__float_as_uint(dinv[s] * dinv[d]) << 32);
      __builtin_nontemporal_store((long long)val, &csr[pos]);
    }
    return;
  }

  const int lane = threadIdx.x & 63;
  const int w = threadIdx.x >> 6;
  const int r = blockIdx.x * 256 + w * 64 + lane;
  const int rid = ids[(r < n) ? r : (n - 1)];
  const float4* __restrict__ xrow = reinterpret_cast<const float4*>(emb + (size_t)rid * 128);

  float acc[64];
  #pragma unroll
  for (int j = 0; j < 64; ++j) acc[j] = 0.f;

  #pragma unroll 1
  for (int s = 0; s < 4; ++s) {
    float4 xb[8];
    #pragma unroll
    for (int i = 0; i < 8; ++i) xb[i] = xrow[s * 8 + i];
    const float* __restrict__ wbase = W1 + (size_t)(s * 32) * 64;
    #pragma unroll
    for (int i = 0; i < 8; ++i) {
      const float* __restrict__ w0 = wbase + (i * 4) * 64;
      #pragma unroll
      for (int j = 0; j < 64; ++j) {
        acc[j] = fmaf(xb[i].x, w0[j], acc[j]);
        acc[j] = fmaf(xb[i].y, w0[64 + j], acc[j]);
        acc[j] = fmaf(xb[i].z, w0[128 + j], acc[j]);
        acc[j] = fmaf(xb[i].w, w0[192 + j], acc[j]);
      }
    }
  }

  if (r < n) {
    u16* op = out + (size_t)r * 64;
    #pragma unroll
    for (int q = 0; q < 8; ++q) {
      uint2 pk;
      pk.x = ((u32)f2bf(acc[q * 4 + 1]) << 16) | f2bf(acc[q * 4 + 0]);
      pk.y = ((u32)f2bf(acc[q * 4 + 3]) << 16) | f2bf(acc[q * 4 + 2]);
      *reinterpret_cast<uint2*>(op + q * 4) = pk;
    }
  }
}

// ---------------- fused aggregation + next-layer GEMM ----------------
// Segments padded to x8: every 8-batch belongs to exactly ONE node. Per batch:
// 8 independent gathers -> 8 FMAs into tmp -> one wave-uniform branch add.

template <bool FINAL>
__global__ __launch_bounds__(256) void k_agg(const u16* __restrict__ xw, const int2* __restrict__ csr,
                                             const int* __restrict__ offs, const float* __restrict__ dinv,
                                             const float* __restrict__ bias, const float* __restrict__ Wn,
                                             u16* __restrict__ out, int n) {
  const int lane = threadIdx.x & 63;
  const int w = threadIdx.x >> 6;
  const float bl = bias[lane];
  const int ngroups = (n + 3) >> 2;
  const int nwaves = gridDim.x * 4;

  for (int grp = blockIdx.x * 4 + w; grp < ngroups; grp += nwaves) {
    const int v0 = grp * 4;
    const int c1 = (v0 + 1 < n) ? v0 + 1 : n;
    const int c2 = (v0 + 2 < n) ? v0 + 2 : n;
    const int c3 = (v0 + 3 < n) ? v0 + 3 : n;
    const int b0 = offs[v0], b1 = offs[c1], b2 = offs[c2], b3 = offs[c3];
    const int b4 = offs[(v0 + 4 < n) ? v0 + 4 : n];

    float d0 = dinv[v0];
    float d1 = dinv[(c1 < n) ? c1 : v0];
    float d2 = dinv[(c2 < n) ? c2 : v0];
    float d3 = dinv[(c3 < n) ? c3 : v0];
    float acc0 = fmaf(bf2f((u32)xw[(size_t)v0 * 64 + lane]), d0 * d0, bl);
    float acc1 = (c1 < n) ? fmaf(bf2f((u32)xw[(size_t)c1 * 64 + lane]), d1 * d1, bl) : 0.f;
    float acc2 = (c2 < n) ? fmaf(bf2f((u32)xw[(size_t)c2 * 64 + lane]), d2 * d2, bl) : 0.f;
    float acc3 = (c3 < n) ? fmaf(bf2f((u32)xw[(size_t)c3 * 64 + lane]), d3 * d3, bl) : 0.f;

    int e = b0;
    while (e < b4) {
      int cnt = b4 - e;
      cnt = (cnt < 64) ? cnt : 64;
      int cex, cey;
      {
        int2 ce = make_int2(0, 0);
        if (lane < cnt) ce = csr[e + lane];
        cex = ce.x; cey = ce.y;
      }
      // uniform 8-edge batches; each batch maps to exactly one node
      for (int bs = 0; bs < cnt; bs += 8) {
        float vv[8];
        #pragma unroll
        for (int t = 0; t < 8; ++t) {
          int sb = __builtin_amdgcn_readlane(cex, bs + t);
          vv[t] = bf2f((u32)xw[(size_t)sb * 64 + lane]);
        }
        float tmp = 0.f;
        #pragma unroll
        for (int t = 0; t < 8; ++t) {
          float cf = __int_as_float(__builtin_amdgcn_readlane(cey, bs + t));
          tmp = fmaf(vv[t], cf, tmp);
        }
        const int ep = e + bs;  // wave-uniform
        if (ep < b1) acc0 += tmp;
        else if (ep < b2) acc1 += tmp;
        else if (ep < b3) acc2 += tmp;
        else acc3 += tmp;
      }
      e += cnt;
    }

    float h0 = fmaxf(acc0, 0.f), h1 = fmaxf(acc1, 0.f);
    float h2 = fmaxf(acc2, 0.f), h3 = fmaxf(acc3, 0.f);
    if constexpr (FINAL) {
      out[(size_t)v0 * 64 + lane] = f2bf(h0);
      if (c1 < n) out[(size_t)c1 * 64 + lane] = f2bf(h1);
      if (c2 < n) out[(size_t)c2 * 64 + lane] = f2bf(h2);
      if (c3 < n) out[(size_t)c3 * 64 + lane] = f2bf(h3);
    } else {
      const int hb0 = __float_as_int(h0), hb1 = __float_as_int(h1);
      const int hb2 = __float_as_int(h2), hb3 = __float_as_int(h3);
      float o0 = 0.f, o1 = 0.f, o2 = 0.f, o3 = 0.f;
      #pragma unroll
      for (int k = 0; k < 64; ++k) {
        float wk = Wn[k * 64 + lane];
        o0 = fmaf(__int_as_float(__builtin_amdgcn_readlane(hb0, k)), wk, o0);
        o1 = fmaf(__int_as_float(__builtin_amdgcn_readlane(hb1, k)), wk, o1);
        o2 = fmaf(__int_as_float(__builtin_amdgcn_readlane(hb2, k)), wk, o2);
        o3 = fmaf(__int_as_float(__builtin_amdgcn_readlane(hb3, k)), wk, o3);
      }
      out[(size_t)v0 * 64 + lane] = f2bf(o0);
      if (c1 < n) out[(size_t)c1 * 64 + lane] = f2bf(o1);
      if (c2 < n) out[(size_t)c2 * 64 + lane] = f2bf(o2);
      if (c3 < n) out[(size_t)c3 * 64 + lane] = f2bf(o3);
    }
  }
}

// ---------------- pooling + MLP head + sigmoid ----------------
__global__ __launch_bounds__(256) void k_pool(const u16* __restrict__ x, const int* __restrict__ batch, int n,
                                              const float* __restrict__ Wf1, const float* __restrict__ bf1,
                                              const float* __restrict__ Wf2, const float* __restrict__ bf2,
                                              float* __restrict__ out) {
  int g = blockIdx.x;
  int tid = threadIdx.x, lane = tid & 63, w = tid >> 6;
  int a = 0, b = n;
  while (a < b) { int m = (a + b) >> 1; if (batch[m] < g) a = m + 1; else b = m; }
  int lo = a;
  b = n;
  while (a < b) { int m = (a + b) >> 1; if (batch[m] < g + 1) a = m + 1; else b = m; }
  int hi = a;

  float acc = 0.f;
  for (int r = lo + w; r < hi; r += 4) acc += bf2f((u32)x[(size_t)r * 64 + lane]);
  __shared__ float red[4][64];
  __shared__ float mean[64];
  red[w][lane] = acc;
  __syncthreads();
  if (w == 0) {
    float s = red[0][lane] + red[1][lane] + red[2][lane] + red[3][lane];
    mean[lane] = s / fmaxf((float)(hi - lo), 1.0f);
  }
  __syncthreads();
  if (w == 0) {
    float h = bf1[lane];
    #pragma unroll
    for (int k = 0; k < 64; ++k) h = fmaf(mean[k], Wf1[k * 64 + lane], h);
    h = fmaxf(h, 0.f);
    float vv = h * Wf2[lane];
    for (int off = 32; off > 0; off >>= 1) vv += __shfl_down(vv, off, 64);
    if (lane == 0) out[g] = 1.0f / (1.0f + expf(-(vv + bf2[0])));
  }
}

static inline char* align256(char* p) {
  return (char*)(((uintptr_t)p + 255) & ~(uintptr_t)255);
}

extern "C" void kernel_launch(void* const* d_in, const int* in_sizes, int n_in,
                              void* d_out, int out_size, void* d_ws, size_t ws_size,
                              hipStream_t stream) {
  const int*   x_ids = (const int*)d_in[0];
  const int*   edge  = (const int*)d_in[1];
  const int*   batch = (const int*)d_in[2];
  const float* emb   = (const float*)d_in[3];
  const float* W1    = (const float*)d_in[4];
  const float* b1    = (const float*)d_in[5];
  const float* W2    = (const float*)d_in[6];
  const float* b2    = (const float*)d_in[7];
  const float* W3    = (const float*)d_in[8];
  const float* b3    = (const float*)d_in[9];
  const float* Wf1   = (const float*)d_in[10];
  const float* bf1   = (const float*)d_in[11];
  const float* Wf2   = (const float*)d_in[12];
  const float* bf2   = (const float*)d_in[13];
  float* out = (float*)d_out;

  const int N = in_sizes[0];
  const int E = in_sizes[1] / 2;
  const int G = out_size;
  const int* e_src = edge;
  const int* e_dst = edge + E;

  const size_t EPAD = (size_t)E + 8 * (size_t)(N + 1) + 64;  // padded csr capacity

  // workspace layout (bf16 feature buffers)
  char* p = (char*)d_ws;
  u16*   bufA = (u16*)p;              p = align256(p + (size_t)N * 64 * 2);
  u16*   bufB = (u16*)p;              p = align256(p + (size_t)N * 64 * 2);
  int2*  csr  = (int2*)p;             p = align256(p + EPAD * 8);
  int*   rank = (int*)p;              p = align256(p + (size_t)E * 4);
  float* dinv = (float*)p;            p = align256(p + (size_t)N * 4);
  int*   cnt  = (int*)p;              p = align256(p + (size_t)N * 4);
  int*   offs = (int*)p;              p = align256(p + (size_t)(N + 1) * 4);
  int*   bsum = (int*)p;              p = align256(p + (size_t)1024 * 4);
  (void)ws_size; (void)n_in;

  const int nb_scan = (N + 1023) / 1024;  // 98 for N=100000 (<=128)
  dim3 blk(256);

  // CSR build (csr pre-zeroed so padding slots are {src=0, coef=0})
  k_init<<<dim3(1024 + 128), blk, 0, stream>>>((int4*)csr, (long long)(EPAD * 2 / 4), cnt, N, 1024);
  k_count_rank<<<dim3((E + 255) / 256), blk, 0, stream>>>(e_dst, cnt, rank, E);
  k_scan1<<<dim3(nb_scan), blk, 0, stream>>>(cnt, N, bsum);
  k_scan2<<<dim3(1), dim3(128), 0, stream>>>(bsum, nb_scan, offs + N);
  k_scan3<<<dim3(nb_scan), blk, 0, stream>>>(cnt, N, bsum, offs, dinv);

  // fused: layer-1 GEMM (blocks [0,mmb)) overlapped with CSR scatter (rest)
  const int mmb = (N + 255) / 256;
  const int scb = (E + 255) / 256;
  k_mm1_scatter<<<dim3(mmb + scb), blk, 0, stream>>>(
      x_ids, emb, W1, bufA, N, mmb,
      e_src, e_dst, rank, dinv, offs, (long long*)csr, E);

  // fused conv+next-GEMM chain (4 nodes/wave, grid-stride)
  k_agg<false><<<dim3(2048), blk, 0, stream>>>(bufA, csr, offs, dinv, b1, W2, bufB, N);
  k_agg<false><<<dim3(2048), blk, 0, stream>>>(bufB, csr, offs, dinv, b2, W3, bufA, N);
  k_agg<true><<<dim3(2048), blk, 0, stream>>>(bufA, csr, offs, dinv, b3, nullptr, bufB, N);

  // pool + MLP head
  k_pool<<<dim3(G), blk, 0, stream>>>(bufB, batch, N, Wf1, bf1, Wf2, bf2, out);
}